// Round 8
// baseline (232.854 us; speedup 1.0000x reference)
//
#include <hip/hip_runtime.h>
#include <hip/hip_bf16.h>

#define N_NODES 20000
#define E_EDGES 320000
#define NH 8
#define NC 32
#define HC 256
#define FIN 41
#define NG 64
#define PCHUNK 16

typedef _Float16 f16x2 __attribute__((ext_vector_type(2)));
typedef _Float16 f16x4 __attribute__((ext_vector_type(4)));
typedef _Float16 f16x8 __attribute__((ext_vector_type(8)));
typedef float f32x4v __attribute__((ext_vector_type(4)));

// ---------------- CSR build ----------------

__global__ __launch_bounds__(256) void init_counts(int* cnt) {
    int n = blockIdx.x * 256 + threadIdx.x;
    if (n < N_NODES) cnt[n] = 1;  // self loop
}

__global__ __launch_bounds__(256) void hist(const int* __restrict__ ei, int* cnt) {
    int e = blockIdx.x * 256 + threadIdx.x;
    if (e < E_EDGES) atomicAdd(&cnt[ei[E_EDGES + e]], 1);
}

__global__ __launch_bounds__(512) void scanA(const int* __restrict__ cnt, int* partial) {
    __shared__ int red[512];
    int n = blockIdx.x * 512 + threadIdx.x;
    int v = (n < N_NODES) ? cnt[n] : 0;
    red[threadIdx.x] = v; __syncthreads();
    for (int off = 256; off > 0; off >>= 1) {
        if (threadIdx.x < off) red[threadIdx.x] += red[threadIdx.x + off];
        __syncthreads();
    }
    if (threadIdx.x == 0) partial[blockIdx.x] = red[0];
}

__global__ __launch_bounds__(64) void scanB(int* partial) {
    int t = threadIdx.x;
    int v = (t < 40) ? partial[t] : 0;
    int orig = v;
    for (int off = 1; off < 64; off <<= 1) {
        int y = __shfl_up(v, off);
        if (t >= off) v += y;
    }
    if (t < 40) partial[t] = v - orig;  // exclusive
}

__global__ __launch_bounds__(512) void scanC(const int* __restrict__ cnt, const int* __restrict__ partial,
                                             int* row_ptr, int* cursor, int* colidx) {
    __shared__ int buf[512];
    int t = threadIdx.x;
    int n = blockIdx.x * 512 + t;
    int v = (n < N_NODES) ? cnt[n] : 0;
    int x = v;
    buf[t] = x; __syncthreads();
    for (int off = 1; off < 512; off <<= 1) {
        int y = (t >= off) ? buf[t - off] : 0;
        __syncthreads();
        x += y; buf[t] = x; __syncthreads();
    }
    int excl = partial[blockIdx.x] + x - v;
    if (n < N_NODES) {
        row_ptr[n] = excl;
        cursor[n] = excl + 1;     // self loop occupies slot 0
        colidx[excl] = n;         // self loop
    }
    if (n == 0) row_ptr[N_NODES] = E_EDGES + N_NODES;
}

__global__ __launch_bounds__(256) void fill_csr(const int* __restrict__ ei, int* cursor, int* colidx) {
    int e = blockIdx.x * 256 + threadIdx.x;
    if (e >= E_EDGES) return;
    int d = ei[E_EDGES + e];
    int s = ei[e];
    int pos = atomicAdd(&cursor[d], 1);
    colidx[pos] = s;
}

// ---------------- W2 -> fp16 col-major via LDS tile transpose ----------------

__global__ __launch_bounds__(256) void wconv(const float* __restrict__ W, _Float16* __restrict__ Wt) {
    __shared__ float tile[64][65];
    int tr = (blockIdx.x >> 2) * 64;   // k-range
    int tc = (blockIdx.x & 3) * 64;    // n-range
    int t = threadIdx.x;
    int rr = t >> 6, cc = t & 63;
#pragma unroll
    for (int j = 0; j < 16; ++j) {
        int row = j * 4 + rr;
        tile[row][cc] = W[(size_t)(tr + row) * 256 + tc + cc];
    }
    __syncthreads();
#pragma unroll
    for (int j = 0; j < 16; ++j) {
        int row = j * 4 + rr;  // n-offset
        Wt[(size_t)(tc + row) * 256 + tr + cc] = (_Float16)tile[cc][row];
    }
}

// ---------------- fc1w [514][64] -> fc1wT [64][520] (row-padded) ----------------

__global__ __launch_bounds__(256) void fc1conv(const float* __restrict__ fc1w, float* __restrict__ fc1wT) {
    int id = blockIdx.x * 256 + threadIdx.x;
    if (id >= 64 * 514) return;
    int u = id / 514, kk = id - u * 514;
    fc1wT[u * 520 + kk] = fc1w[kk * 64 + u];
}

// ---------------- GEMM K=256 via MFMA fp16 + fused score dots ----------------
// block = 32 rows x 256 cols, 8 waves (512 thr); wave w = head w: cols [w*32, w*32+32).
// wave computes 2x2 tiles of 16x16; 4 loads : 4 MFMAs per K-step; 2-deep reg pipeline.

__global__ __launch_bounds__(512) void gemm256h(const _Float16* __restrict__ Xh,
                                                const _Float16* __restrict__ Wt,
                                                const float* __restrict__ a_src,
                                                const float* __restrict__ a_dst,
                                                _Float16* __restrict__ Hh,
                                                float* __restrict__ ssrc,
                                                float* __restrict__ sdst) {
    __shared__ _Float16 hs[32 * 264];
    int row0 = blockIdx.x * 32;
    int tid = threadIdx.x;
    int lane = tid & 63;
    int w = tid >> 6;          // head 0..7
    int r16 = lane & 15;
    int kseg = lane >> 4;

    f32x4v acc[2][2];
#pragma unroll
    for (int a = 0; a < 2; ++a)
#pragma unroll
        for (int b = 0; b < 2; ++b) acc[a][b] = (f32x4v){0.f, 0.f, 0.f, 0.f};

    const _Float16* XA = Xh + (size_t)(row0 + r16) * 256 + kseg * 4;
    const _Float16* WB = Wt + (size_t)(w * 32 + r16) * 256 + kseg * 4;

    f16x4 a0[2], a1[2], b0[2], b1[2];
#define LOADF(st, koff)                                   \
    a0[st] = *(const f16x4*)(XA + (koff));                \
    a1[st] = *(const f16x4*)(XA + 16 * 256 + (koff));     \
    b0[st] = *(const f16x4*)(WB + (koff));                \
    b1[st] = *(const f16x4*)(WB + 16 * 256 + (koff));

    LOADF(0, 0)
#pragma unroll
    for (int s = 0; s < 16; ++s) {
        const int cur = s & 1, nxt = cur ^ 1;
        if (s < 15) { LOADF(nxt, (s + 1) * 16) }
        acc[0][0] = __builtin_amdgcn_mfma_f32_16x16x16f16(a0[cur], b0[cur], acc[0][0], 0, 0, 0);
        acc[0][1] = __builtin_amdgcn_mfma_f32_16x16x16f16(a0[cur], b1[cur], acc[0][1], 0, 0, 0);
        acc[1][0] = __builtin_amdgcn_mfma_f32_16x16x16f16(a1[cur], b0[cur], acc[1][0], 0, 0, 0);
        acc[1][1] = __builtin_amdgcn_mfma_f32_16x16x16f16(a1[cur], b1[cur], acc[1][1], 0, 0, 0);
    }
#undef LOADF

    // fused attention-score dots: wave w covers exactly head w (32 cols)
    float as0 = a_src[w * 32 + r16], as1 = a_src[w * 32 + 16 + r16];
    float ad0 = a_dst[w * 32 + r16], ad1 = a_dst[w * 32 + 16 + r16];
#pragma unroll
    for (int tm = 0; tm < 2; ++tm) {
#pragma unroll
        for (int r = 0; r < 4; ++r) {
            float p = acc[tm][0][r] * as0 + acc[tm][1][r] * as1;
            float q = acc[tm][0][r] * ad0 + acc[tm][1][r] * ad1;
            p += __shfl_xor(p, 1); q += __shfl_xor(q, 1);
            p += __shfl_xor(p, 2); q += __shfl_xor(q, 2);
            p += __shfl_xor(p, 4); q += __shfl_xor(q, 4);
            p += __shfl_xor(p, 8); q += __shfl_xor(q, 8);
            if (r16 == 0) {
                int row = row0 + tm * 16 + kseg * 4 + r;
                ssrc[row * NH + w] = p;
                sdst[row * NH + w] = q;
            }
        }
    }

    // H (fp16) via LDS transpose for coalesced 16B stores
#pragma unroll
    for (int tm = 0; tm < 2; ++tm)
#pragma unroll
        for (int tn = 0; tn < 2; ++tn)
#pragma unroll
            for (int r = 0; r < 4; ++r)
                hs[(tm * 16 + kseg * 4 + r) * 264 + w * 32 + tn * 16 + r16] = (_Float16)acc[tm][tn][r];
    __syncthreads();
#pragma unroll
    for (int i = 0; i < 2; ++i) {
        int idx = i * 512 + tid;
        int rr = idx >> 5;
        int cc = idx & 31;
        f16x8 v = *(const f16x8*)&hs[rr * 264 + cc * 8];
        *(f16x8*)(Hh + (size_t)(row0 + rr) * 256 + cc * 8) = v;
    }
}

// ---------------- GEMM K=41 (fp32 VALU) + fused score dots, fp16 H out ----------------
// BM=16, grid 1250 -> ~19.5 waves/CU.

__global__ __launch_bounds__(256) void gemm41(const float* __restrict__ X,
                                              const float* __restrict__ W,
                                              const float* __restrict__ a_src,
                                              const float* __restrict__ a_dst,
                                              _Float16* __restrict__ Hh,
                                              float* __restrict__ ssrc,
                                              float* __restrict__ sdst) {
    __shared__ float xs[16][44];
    int row0 = blockIdx.x * 16;
    int tid = threadIdx.x;
    int lane = tid & 63;
    int wave = tid >> 6;
    int c4 = lane * 4;
    int wrow = wave * 4;

    for (int idx = tid; idx < 16 * FIN; idx += 256) {
        int r = idx / FIN, k = idx - r * FIN;
        xs[r][k] = X[(size_t)(row0 + r) * FIN + k];
    }
    __syncthreads();

    float4 acc[4];
#pragma unroll
    for (int r = 0; r < 4; ++r) acc[r] = make_float4(0.f, 0.f, 0.f, 0.f);

    for (int k = 0; k < FIN; ++k) {
        float4 w0 = *reinterpret_cast<const float4*>(W + (size_t)k * HC + c4);
#pragma unroll
        for (int r = 0; r < 4; ++r) {
            float xv = xs[wrow + r][k];
            acc[r].x += xv * w0.x; acc[r].y += xv * w0.y; acc[r].z += xv * w0.z; acc[r].w += xv * w0.w;
        }
    }
    const float4 asv = *reinterpret_cast<const float4*>(a_src + c4);
    const float4 adv = *reinterpret_cast<const float4*>(a_dst + c4);
#pragma unroll
    for (int r = 0; r < 4; ++r) {
        int gr = row0 + wrow + r;
        f16x4 hv;
        hv[0] = (_Float16)acc[r].x; hv[1] = (_Float16)acc[r].y;
        hv[2] = (_Float16)acc[r].z; hv[3] = (_Float16)acc[r].w;
        *(f16x4*)(Hh + (size_t)gr * HC + c4) = hv;
        float ps = acc[r].x * asv.x + acc[r].y * asv.y + acc[r].z * asv.z + acc[r].w * asv.w;
        float pd = acc[r].x * adv.x + acc[r].y * adv.y + acc[r].z * adv.z + acc[r].w * adv.w;
        ps += __shfl_xor(ps, 1); pd += __shfl_xor(pd, 1);
        ps += __shfl_xor(ps, 2); pd += __shfl_xor(pd, 2);
        ps += __shfl_xor(ps, 4); pd += __shfl_xor(pd, 4);
        if ((lane & 7) == 0) {
            ssrc[gr * NH + (lane >> 3)] = ps;
            sdst[gr * NH + (lane >> 3)] = pd;
        }
    }
}

// ---------------- fused GAT aggregation + bias + BN(eval) + ELU ----------------
// One wave per dst node. Phase 2: dual-edge half-waves — lanes 0..31 even edges,
// lanes 32..63 odd edges; each lane covers 8 channels (f16x8 16B load); x4 unroll
// = 4 independent 16B gather chains per lane. Halves merged via shfl_xor(...,32).
// Output fp16 always.

__global__ __launch_bounds__(256) void gat_agg(const int* __restrict__ row_ptr,
                                               const int* __restrict__ colidx,
                                               const float* __restrict__ ssrc,
                                               const float* __restrict__ sdst,
                                               const _Float16* __restrict__ h,
                                               const float* __restrict__ bias,
                                               const float* __restrict__ gamma,
                                               const float* __restrict__ beta,
                                               _Float16* __restrict__ outh) {
    int wid = (blockIdx.x * blockDim.x + threadIdx.x) >> 6;
    int lane = threadIdx.x & 63;
    if (wid >= N_NODES) return;
    int n = wid;
    int beg = row_ptr[n], end = row_ptr[n + 1];
    int deg = end - beg;

    // phase 1: per-head max (8 edge-slots x 8 heads)
    int hd1 = lane & 7;
    float sd1 = sdst[n * NH + hd1];
    float mx = -3.0e38f;
    for (int i = (lane >> 3); i < deg; i += 8) {
        int s = colidx[beg + i];
        float v = ssrc[s * NH + hd1] + sd1;
        v = (v >= 0.f) ? v : 0.2f * v;
        mx = fmaxf(mx, v);
    }
    mx = fmaxf(mx, __shfl_xor(mx, 8));
    mx = fmaxf(mx, __shfl_xor(mx, 16));
    mx = fmaxf(mx, __shfl_xor(mx, 32));
    // every lane now holds max for head (lane&7)

    // phase 2: dual-edge accumulate
    int half = lane >> 5;          // 0: even edges, 1: odd edges
    int ll = lane & 31;
    int hd2 = ll >> 2;             // head of this lane's channels
    int ch8 = ll * 8;              // channel base (8 channels)
    float m2 = __shfl(mx, hd2);
    float sd2 = sdst[n * NH + hd2];

    float acc[8] = {0.f, 0.f, 0.f, 0.f, 0.f, 0.f, 0.f, 0.f};
    float denom = 0.f;

    int i = half;
    for (; i + 6 < deg; i += 8) {
        int s0 = colidx[beg + i];
        int s1 = colidx[beg + i + 2];
        int s2 = colidx[beg + i + 4];
        int s3 = colidx[beg + i + 6];
        float v0 = ssrc[s0 * NH + hd2] + sd2; v0 = (v0 >= 0.f) ? v0 : 0.2f * v0;
        float v1 = ssrc[s1 * NH + hd2] + sd2; v1 = (v1 >= 0.f) ? v1 : 0.2f * v1;
        float v2 = ssrc[s2 * NH + hd2] + sd2; v2 = (v2 >= 0.f) ? v2 : 0.2f * v2;
        float v3 = ssrc[s3 * NH + hd2] + sd2; v3 = (v3 >= 0.f) ? v3 : 0.2f * v3;
        float w0 = __expf(v0 - m2);
        float w1 = __expf(v1 - m2);
        float w2 = __expf(v2 - m2);
        float w3 = __expf(v3 - m2);
        f16x8 h0 = *(const f16x8*)(h + (size_t)s0 * HC + ch8);
        f16x8 h1 = *(const f16x8*)(h + (size_t)s1 * HC + ch8);
        f16x8 h2 = *(const f16x8*)(h + (size_t)s2 * HC + ch8);
        f16x8 h3 = *(const f16x8*)(h + (size_t)s3 * HC + ch8);
        denom += (w0 + w1) + (w2 + w3);
#pragma unroll
        for (int j = 0; j < 8; ++j)
            acc[j] += w0 * (float)h0[j] + w1 * (float)h1[j] + w2 * (float)h2[j] + w3 * (float)h3[j];
    }
    for (; i < deg; i += 2) {
        int s = colidx[beg + i];
        float v = ssrc[s * NH + hd2] + sd2;
        v = (v >= 0.f) ? v : 0.2f * v;
        float wgt = __expf(v - m2);
        f16x8 hv = *(const f16x8*)(h + (size_t)s * HC + ch8);
        denom += wgt;
#pragma unroll
        for (int j = 0; j < 8; ++j) acc[j] += wgt * (float)hv[j];
    }

    // merge halves
#pragma unroll
    for (int j = 0; j < 8; ++j) acc[j] += __shfl_xor(acc[j], 32);
    denom += __shfl_xor(denom, 32);

    if (half == 0) {
        float inv = 1.0f / denom;
        const float bninv = 0.99999500003749981f;  // 1/sqrt(1+1e-5)
        float4 b0v = *(const float4*)(bias + ch8);
        float4 b1v = *(const float4*)(bias + ch8 + 4);
        float4 g0v = *(const float4*)(gamma + ch8);
        float4 g1v = *(const float4*)(gamma + ch8 + 4);
        float4 e0v = *(const float4*)(beta + ch8);
        float4 e1v = *(const float4*)(beta + ch8 + 4);
        float bb[8] = {b0v.x, b0v.y, b0v.z, b0v.w, b1v.x, b1v.y, b1v.z, b1v.w};
        float gg[8] = {g0v.x, g0v.y, g0v.z, g0v.w, g1v.x, g1v.y, g1v.z, g1v.w};
        float ee[8] = {e0v.x, e0v.y, e0v.z, e0v.w, e1v.x, e1v.y, e1v.z, e1v.w};
        f16x8 o;
#pragma unroll
        for (int j = 0; j < 8; ++j) {
            float v = acc[j] * inv + bb[j];
            v = v * (gg[j] * bninv) + ee[j];
            v = (v > 0.f) ? v : (__expf(v) - 1.0f);
            o[j] = (_Float16)v;
        }
        *(f16x8*)(outh + (size_t)n * HC + ch8) = o;
    }
}

// ---------------- pooling ----------------

__global__ __launch_bounds__(256) void graph_ranges(const int* __restrict__ batch, int* gstart, int* gend) {
    int n = blockIdx.x * 256 + threadIdx.x;
    if (n >= N_NODES) return;
    int b = batch[n];
    if (n == 0) gstart[b] = 0;
    else {
        int pb = batch[n - 1];
        if (pb != b) { gstart[b] = n; gend[pb] = n; }
    }
    if (n == N_NODES - 1) gend[b] = N_NODES;
}

// fp16 input; 128 threads, each owns 2 channels (f16x2 -> full 512B row width/wave-pair)
__global__ __launch_bounds__(128) void pool_partial(const _Float16* __restrict__ h,
                                                    const int* __restrict__ gstart,
                                                    const int* __restrict__ gend,
                                                    float* __restrict__ psum,
                                                    float* __restrict__ pmax) {
    int g = blockIdx.x >> 4;
    int c = blockIdx.x & (PCHUNK - 1);
    int t = threadIdx.x;
    int ch2 = t * 2;
    int s = gstart[g], e = gend[g];
    int len = e - s;
    int n0 = s + (int)(((long long)len * c) / PCHUNK);
    int n1 = s + (int)(((long long)len * (c + 1)) / PCHUNK);
    float s0 = 0.f, s1 = 0.f, m0 = -3.0e38f, m1 = -3.0e38f;
    for (int n = n0; n < n1; ++n) {
        f16x2 v = *(const f16x2*)(h + (size_t)n * HC + ch2);
        float f0 = (float)v[0], f1 = (float)v[1];
        s0 += f0; s1 += f1;
        m0 = fmaxf(m0, f0); m1 = fmaxf(m1, f1);
    }
    size_t base = (size_t)(g * PCHUNK + c) * HC + ch2;
    *(float2*)(psum + base) = make_float2(s0, s1);
    *(float2*)(pmax + base) = make_float2(m0, m1);
}

// ---------------- MLP head (fused pool-finalize + 3 FC layers) ----------------

__global__ __launch_bounds__(256) void mlp(const float* __restrict__ psum,
                                           const float* __restrict__ pmax,
                                           const int* __restrict__ gstart,
                                           const int* __restrict__ gend,
                                           const float* __restrict__ gsz,
                                           const float* __restrict__ fc1wT, const float* __restrict__ fc1b,
                                           const float* __restrict__ gf1, const float* __restrict__ bf1,
                                           const float* __restrict__ fc2w, const float* __restrict__ fc2b,
                                           const float* __restrict__ gf2, const float* __restrict__ bf2,
                                           const float* __restrict__ fc3w, const float* __restrict__ fc3b,
                                           float* __restrict__ out) {
    __shared__ __align__(16) float pr[514];
    __shared__ float z1[64];
    __shared__ float zz2[8][32];
    __shared__ float z2[32];
    int g = blockIdx.x;
    int t = threadIdx.x;
    const float bninv = 0.99999500003749981f;

    // phase 0: reduce pool partials
    {
        float s = 0.f, m = -3.0e38f;
#pragma unroll
        for (int c = 0; c < PCHUNK; ++c) {
            s += psum[(size_t)(g * PCHUNK + c) * HC + t];
            m = fmaxf(m, pmax[(size_t)(g * PCHUNK + c) * HC + t]);
        }
        float cnt = (float)(gend[g] - gstart[g]);
        pr[t] = s / fmaxf(cnt, 1.f);
        pr[256 + t] = m;
        if (t < 2) pr[512 + t] = gsz[g * 2 + t];
    }
    __syncthreads();

    // phase 1: fc1 (514 x 64): wave wv computes outputs wv*16..wv*16+15
    {
        int wv = t >> 6, lane = t & 63;
        float4 pa = *reinterpret_cast<const float4*>(&pr[lane * 8]);
        float4 pb = *reinterpret_cast<const float4*>(&pr[lane * 8 + 4]);
#pragma unroll 4
        for (int i = 0; i < 16; ++i) {
            int u = wv * 16 + i;
            const float* wrow = fc1wT + u * 520;
            float4 wa = *reinterpret_cast<const float4*>(wrow + lane * 8);
            float4 wb = *reinterpret_cast<const float4*>(wrow + lane * 8 + 4);
            float a = pa.x * wa.x + pa.y * wa.y + pa.z * wa.z + pa.w * wa.w
                    + pb.x * wb.x + pb.y * wb.y + pb.z * wb.z + pb.w * wb.w;
            if (lane == 0) a += pr[512] * wrow[512] + pr[513] * wrow[513];
            a += __shfl_xor(a, 1); a += __shfl_xor(a, 2); a += __shfl_xor(a, 4);
            a += __shfl_xor(a, 8); a += __shfl_xor(a, 16); a += __shfl_xor(a, 32);
            if (lane == 0) {
                a += fc1b[u];
                a = a * (gf1[u] * bninv) + bf1[u];
                z1[u] = fmaxf(a, 0.f);
            }
        }
    }
    __syncthreads();

    // phase 2: fc2 (64 x 32), 8-way k-split
    {
        int u = t & 31, sp = t >> 5;
        float b = 0.f;
#pragma unroll
        for (int k = sp * 8; k < sp * 8 + 8; ++k) b += z1[k] * fc2w[k * 32 + u];
        zz2[sp][u] = b;
    }
    __syncthreads();
    if (t < 32) {
        float b = 0.f;
#pragma unroll
        for (int sp = 0; sp < 8; ++sp) b += zz2[sp][t];
        b += fc2b[t];
        b = b * (gf2[t] * bninv) + bf2[t];
        z2[t] = fmaxf(b, 0.f);
    }
    __syncthreads();

    // phase 3: fc3 (32 x 2)
    if (t < 2) {
        float c = 0.f;
#pragma unroll
        for (int k = 0; k < 32; ++k) c += z2[k] * fc3w[k * 2 + t];
        out[g * 2 + t] = c + fc3b[t];
    }
}

// ---------------- launch ----------------

extern "C" void kernel_launch(void* const* d_in, const int* in_sizes, int n_in,
                              void* d_out, int out_size, void* d_ws, size_t ws_size,
                              hipStream_t stream) {
    const float* x    = (const float*)d_in[0];
    const int*   ei   = (const int*)d_in[1];
    const int*   batch= (const int*)d_in[2];
    const float* gsz  = (const float*)d_in[3];
    const float* W1   = (const float*)d_in[4];
    const float* as1  = (const float*)d_in[5];
    const float* ad1  = (const float*)d_in[6];
    const float* b1   = (const float*)d_in[7];
    const float* g1   = (const float*)d_in[8];
    const float* be1  = (const float*)d_in[9];
    const float* W2   = (const float*)d_in[10];
    const float* as2  = (const float*)d_in[11];
    const float* ad2  = (const float*)d_in[12];
    const float* b2   = (const float*)d_in[13];
    const float* g2   = (const float*)d_in[14];
    const float* be2  = (const float*)d_in[15];
    const float* fc1w = (const float*)d_in[16];
    const float* fc1b = (const float*)d_in[17];
    const float* gf1  = (const float*)d_in[18];
    const float* bf1  = (const float*)d_in[19];
    const float* fc2w = (const float*)d_in[20];
    const float* fc2b = (const float*)d_in[21];
    const float* gf2  = (const float*)d_in[22];
    const float* bf2  = (const float*)d_in[23];
    const float* fc3w = (const float*)d_in[24];
    const float* fc3b = (const float*)d_in[25];
    float* out = (float*)d_out;

    char* w = (char*)d_ws;
    _Float16* h_half   = (_Float16*)w; w += (size_t)N_NODES * HC * 2;   // 10.24 MB
    _Float16* act_half = (_Float16*)w; w += (size_t)N_NODES * HC * 2;   // 10.24 MB
    _Float16* act2_half= (_Float16*)w; w += (size_t)N_NODES * HC * 2;   // 10.24 MB
    _Float16* Wt       = (_Float16*)w; w += (size_t)HC * HC * 2;        // 128 KB
    float* fc1wT       = (float*)w;    w += (size_t)64 * 520 * 4;       // 133 KB
    float* ssrc        = (float*)w;    w += (size_t)N_NODES * NH * 4;
    float* sdst        = (float*)w;    w += (size_t)N_NODES * NH * 4;
    int* row_ptr  = (int*)w;   w += (size_t)(N_NODES + 1) * 4;
    int* cursor   = (int*)w;   w += (size_t)N_NODES * 4;
    int* cnt      = (int*)w;   w += (size_t)N_NODES * 4;
    int* colidx   = (int*)w;   w += (size_t)(E_EDGES + N_NODES) * 4;
    int* partial  = (int*)w;   w += 64 * 4;
    int* gstart   = (int*)w;   w += 64 * 4;
    int* gend     = (int*)w;   w += 64 * 4;

    // pool partials alias h_half (dead after gat_agg#2)
    float* psum = (float*)h_half;
    float* pmax = psum + (size_t)NG * PCHUNK * HC;

    hipMemsetAsync(gstart, 0, 2 * 64 * 4, stream);

    init_counts<<<79, 256, 0, stream>>>(cnt);
    hist<<<1250, 256, 0, stream>>>(ei, cnt);
    scanA<<<40, 512, 0, stream>>>(cnt, partial);
    scanB<<<1, 64, 0, stream>>>(partial);
    scanC<<<40, 512, 0, stream>>>(cnt, partial, row_ptr, cursor, colidx);
    fill_csr<<<1250, 256, 0, stream>>>(ei, cursor, colidx);
    wconv<<<16, 256, 0, stream>>>(W2, Wt);
    fc1conv<<<129, 256, 0, stream>>>(fc1w, fc1wT);

    gemm41<<<1250, 256, 0, stream>>>(x, W1, as1, ad1, h_half, ssrc, sdst);
    gat_agg<<<5000, 256, 0, stream>>>(row_ptr, colidx, ssrc, sdst, h_half, b1, g1, be1, act_half);

    gemm256h<<<625, 512, 0, stream>>>(act_half, Wt, as2, ad2, h_half, ssrc, sdst);
    gat_agg<<<5000, 256, 0, stream>>>(row_ptr, colidx, ssrc, sdst, h_half, b2, g2, be2, act2_half);

    graph_ranges<<<79, 256, 0, stream>>>(batch, gstart, gend);
    pool_partial<<<NG * PCHUNK, 128, 0, stream>>>(act2_half, gstart, gend, psum, pmax);
    mlp<<<NG, 256, 0, stream>>>(psum, pmax, gstart, gend, gsz,
                                fc1wT, fc1b, gf1, bf1, fc2w, fc2b, gf2, bf2, fc3w, fc3b, out);
}

// Round 9
// 193.379 us; speedup vs baseline: 1.2041x; 1.2041x over previous
//
#include <hip/hip_runtime.h>
#include <hip/hip_bf16.h>

#define N_NODES 20000
#define E_EDGES 320000
#define NH 8
#define NC 32
#define HC 256
#define FIN 41
#define NG 64
#define PCHUNK 16

typedef _Float16 f16x4 __attribute__((ext_vector_type(4)));
typedef _Float16 f16x8 __attribute__((ext_vector_type(8)));
typedef float f32x4v __attribute__((ext_vector_type(4)));

// ---------------- CSR build ----------------

__global__ __launch_bounds__(256) void init_counts(int* cnt) {
    int n = blockIdx.x * 256 + threadIdx.x;
    if (n < N_NODES) cnt[n] = 1;  // self loop
}

__global__ __launch_bounds__(256) void hist(const int* __restrict__ ei, int* cnt) {
    int e = blockIdx.x * 256 + threadIdx.x;
    if (e < E_EDGES) atomicAdd(&cnt[ei[E_EDGES + e]], 1);
}

__global__ __launch_bounds__(512) void scanA(const int* __restrict__ cnt, int* partial) {
    __shared__ int red[512];
    int n = blockIdx.x * 512 + threadIdx.x;
    int v = (n < N_NODES) ? cnt[n] : 0;
    red[threadIdx.x] = v; __syncthreads();
    for (int off = 256; off > 0; off >>= 1) {
        if (threadIdx.x < off) red[threadIdx.x] += red[threadIdx.x + off];
        __syncthreads();
    }
    if (threadIdx.x == 0) partial[blockIdx.x] = red[0];
}

__global__ __launch_bounds__(64) void scanB(int* partial) {
    int t = threadIdx.x;
    int v = (t < 40) ? partial[t] : 0;
    int orig = v;
    for (int off = 1; off < 64; off <<= 1) {
        int y = __shfl_up(v, off);
        if (t >= off) v += y;
    }
    if (t < 40) partial[t] = v - orig;  // exclusive
}

__global__ __launch_bounds__(512) void scanC(const int* __restrict__ cnt, const int* __restrict__ partial,
                                             int* row_ptr, int* cursor, int* colidx) {
    __shared__ int buf[512];
    int t = threadIdx.x;
    int n = blockIdx.x * 512 + t;
    int v = (n < N_NODES) ? cnt[n] : 0;
    int x = v;
    buf[t] = x; __syncthreads();
    for (int off = 1; off < 512; off <<= 1) {
        int y = (t >= off) ? buf[t - off] : 0;
        __syncthreads();
        x += y; buf[t] = x; __syncthreads();
    }
    int excl = partial[blockIdx.x] + x - v;
    if (n < N_NODES) {
        row_ptr[n] = excl;
        cursor[n] = excl + 1;     // self loop occupies slot 0
        colidx[excl] = n;         // self loop
    }
    if (n == 0) row_ptr[N_NODES] = E_EDGES + N_NODES;
}

__global__ __launch_bounds__(256) void fill_csr(const int* __restrict__ ei, int* cursor, int* colidx) {
    int e = blockIdx.x * 256 + threadIdx.x;
    if (e >= E_EDGES) return;
    int d = ei[E_EDGES + e];
    int s = ei[e];
    int pos = atomicAdd(&cursor[d], 1);
    colidx[pos] = s;
}

// ---------------- W2 -> fp16 col-major via LDS tile transpose ----------------

__global__ __launch_bounds__(256) void wconv(const float* __restrict__ W, _Float16* __restrict__ Wt) {
    __shared__ float tile[64][65];
    int tr = (blockIdx.x >> 2) * 64;   // k-range
    int tc = (blockIdx.x & 3) * 64;    // n-range
    int t = threadIdx.x;
    int rr = t >> 6, cc = t & 63;
#pragma unroll
    for (int j = 0; j < 16; ++j) {
        int row = j * 4 + rr;
        tile[row][cc] = W[(size_t)(tr + row) * 256 + tc + cc];
    }
    __syncthreads();
#pragma unroll
    for (int j = 0; j < 16; ++j) {
        int row = j * 4 + rr;  // n-offset
        Wt[(size_t)(tc + row) * 256 + tr + cc] = (_Float16)tile[cc][row];
    }
}

// ---------------- fc1w [514][64] -> fc1wT [64][520] (row-padded) ----------------

__global__ __launch_bounds__(256) void fc1conv(const float* __restrict__ fc1w, float* __restrict__ fc1wT) {
    int id = blockIdx.x * 256 + threadIdx.x;
    if (id >= 64 * 514) return;
    int u = id / 514, kk = id - u * 514;
    fc1wT[u * 520 + kk] = fc1w[kk * 64 + u];
}

// ---------------- GEMM K=256 via MFMA fp16 (16x16x32) + fused score dots ----------------
// block = 32 rows x 256 cols, 4 waves; wave w: cols [w*64, w*64+64) = heads 2w,2w+1.
// K-steps of 32: per-lane f16x8 (16B) fragments -> 64B-aligned segments, 8 steps,
// 6 loads : 8 MFMAs per step, 2-deep register pipeline.
// A: lane holds X[row0+(l&15)][k0+8*(l>>4)+j], j=0..7; B: Wt[col][k] same k-map.
// D: col=l&15, row=4*(l>>4)+r (m89-verified, dtype-independent).

__global__ __launch_bounds__(256) void gemm256h(const _Float16* __restrict__ Xh,
                                                const _Float16* __restrict__ Wt,
                                                const float* __restrict__ a_src,
                                                const float* __restrict__ a_dst,
                                                _Float16* __restrict__ Hh,
                                                float* __restrict__ ssrc,
                                                float* __restrict__ sdst) {
    __shared__ _Float16 hs[32 * 264];
    int row0 = blockIdx.x * 32;
    int tid = threadIdx.x;
    int lane = tid & 63;
    int w = tid >> 6;
    int r16 = lane & 15;
    int kseg = lane >> 4;

    f32x4v acc[2][4];
#pragma unroll
    for (int a = 0; a < 2; ++a)
#pragma unroll
        for (int b = 0; b < 4; ++b) acc[a][b] = (f32x4v){0.f, 0.f, 0.f, 0.f};

    const _Float16* XA = Xh + (size_t)(row0 + r16) * 256 + kseg * 8;
    const _Float16* WB = Wt + (size_t)(w * 64 + r16) * 256 + kseg * 8;

    f16x8 a0[2], a1[2], b0[2], b1[2], b2[2], b3[2];
#define LOADF(st, koff)                                   \
    a0[st] = *(const f16x8*)(XA + (koff));                \
    a1[st] = *(const f16x8*)(XA + 16 * 256 + (koff));     \
    b0[st] = *(const f16x8*)(WB + (koff));                \
    b1[st] = *(const f16x8*)(WB + 16 * 256 + (koff));     \
    b2[st] = *(const f16x8*)(WB + 32 * 256 + (koff));     \
    b3[st] = *(const f16x8*)(WB + 48 * 256 + (koff));

    LOADF(0, 0)
#pragma unroll
    for (int s = 0; s < 8; ++s) {
        const int cur = s & 1, nxt = cur ^ 1;
        if (s < 7) { LOADF(nxt, (s + 1) * 32) }
        acc[0][0] = __builtin_amdgcn_mfma_f32_16x16x32_f16(a0[cur], b0[cur], acc[0][0], 0, 0, 0);
        acc[0][1] = __builtin_amdgcn_mfma_f32_16x16x32_f16(a0[cur], b1[cur], acc[0][1], 0, 0, 0);
        acc[0][2] = __builtin_amdgcn_mfma_f32_16x16x32_f16(a0[cur], b2[cur], acc[0][2], 0, 0, 0);
        acc[0][3] = __builtin_amdgcn_mfma_f32_16x16x32_f16(a0[cur], b3[cur], acc[0][3], 0, 0, 0);
        acc[1][0] = __builtin_amdgcn_mfma_f32_16x16x32_f16(a1[cur], b0[cur], acc[1][0], 0, 0, 0);
        acc[1][1] = __builtin_amdgcn_mfma_f32_16x16x32_f16(a1[cur], b1[cur], acc[1][1], 0, 0, 0);
        acc[1][2] = __builtin_amdgcn_mfma_f32_16x16x32_f16(a1[cur], b2[cur], acc[1][2], 0, 0, 0);
        acc[1][3] = __builtin_amdgcn_mfma_f32_16x16x32_f16(a1[cur], b3[cur], acc[1][3], 0, 0, 0);
    }
#undef LOADF

    // fused attention-score dots: wave w's 64 cols = heads 2w, 2w+1 complete
    float as0 = a_src[w * 64 + r16],      as1 = a_src[w * 64 + 16 + r16];
    float as2 = a_src[w * 64 + 32 + r16], as3 = a_src[w * 64 + 48 + r16];
    float ad0 = a_dst[w * 64 + r16],      ad1 = a_dst[w * 64 + 16 + r16];
    float ad2 = a_dst[w * 64 + 32 + r16], ad3 = a_dst[w * 64 + 48 + r16];
#pragma unroll
    for (int tm = 0; tm < 2; ++tm) {
#pragma unroll
        for (int r = 0; r < 4; ++r) {
            float p0 = acc[tm][0][r] * as0 + acc[tm][1][r] * as1;
            float p1 = acc[tm][2][r] * as2 + acc[tm][3][r] * as3;
            float q0 = acc[tm][0][r] * ad0 + acc[tm][1][r] * ad1;
            float q1 = acc[tm][2][r] * ad2 + acc[tm][3][r] * ad3;
#pragma unroll
            for (int m = 1; m < 16; m <<= 1) {
                p0 += __shfl_xor(p0, m); p1 += __shfl_xor(p1, m);
                q0 += __shfl_xor(q0, m); q1 += __shfl_xor(q1, m);
            }
            if (r16 == 0) {
                int row = row0 + tm * 16 + kseg * 4 + r;
                ssrc[row * NH + w * 2]     = p0;
                ssrc[row * NH + w * 2 + 1] = p1;
                sdst[row * NH + w * 2]     = q0;
                sdst[row * NH + w * 2 + 1] = q1;
            }
        }
    }

    // H (fp16) via LDS transpose for coalesced 16B stores
#pragma unroll
    for (int tm = 0; tm < 2; ++tm)
#pragma unroll
        for (int tn = 0; tn < 4; ++tn)
#pragma unroll
            for (int r = 0; r < 4; ++r)
                hs[(tm * 16 + kseg * 4 + r) * 264 + w * 64 + tn * 16 + r16] = (_Float16)acc[tm][tn][r];
    __syncthreads();
#pragma unroll
    for (int i = 0; i < 4; ++i) {
        int idx = i * 256 + tid;
        int rr = idx >> 5;
        int cc = idx & 31;
        f16x8 v = *(const f16x8*)&hs[rr * 264 + cc * 8];
        *(f16x8*)(Hh + (size_t)(row0 + rr) * 256 + cc * 8) = v;
    }
}

// ---------------- GEMM K=41 (fp32 VALU) + fused score dots, fp16 H out ----------------

__global__ __launch_bounds__(256) void gemm41(const float* __restrict__ X,
                                              const float* __restrict__ W,
                                              const float* __restrict__ a_src,
                                              const float* __restrict__ a_dst,
                                              _Float16* __restrict__ Hh,
                                              float* __restrict__ ssrc,
                                              float* __restrict__ sdst) {
    __shared__ float xs[32][44];
    int row0 = blockIdx.x * 32;
    int tid = threadIdx.x;
    int lane = tid & 63;
    int wave = tid >> 6;
    int c4 = lane * 4;
    int wrow = wave * 8;

    for (int idx = tid; idx < 32 * FIN; idx += 256) {
        int r = idx / FIN, k = idx - r * FIN;
        xs[r][k] = X[(size_t)(row0 + r) * FIN + k];
    }
    __syncthreads();

    float4 acc[8];
#pragma unroll
    for (int r = 0; r < 8; ++r) acc[r] = make_float4(0.f, 0.f, 0.f, 0.f);

    for (int k = 0; k < FIN; ++k) {
        float4 w0 = *reinterpret_cast<const float4*>(W + (size_t)k * HC + c4);
#pragma unroll
        for (int r = 0; r < 8; ++r) {
            float xv = xs[wrow + r][k];
            acc[r].x += xv * w0.x; acc[r].y += xv * w0.y; acc[r].z += xv * w0.z; acc[r].w += xv * w0.w;
        }
    }
    const float4 asv = *reinterpret_cast<const float4*>(a_src + c4);
    const float4 adv = *reinterpret_cast<const float4*>(a_dst + c4);
#pragma unroll
    for (int r = 0; r < 8; ++r) {
        int gr = row0 + wrow + r;
        f16x4 hv;
        hv[0] = (_Float16)acc[r].x; hv[1] = (_Float16)acc[r].y;
        hv[2] = (_Float16)acc[r].z; hv[3] = (_Float16)acc[r].w;
        *(f16x4*)(Hh + (size_t)gr * HC + c4) = hv;
        float ps = acc[r].x * asv.x + acc[r].y * asv.y + acc[r].z * asv.z + acc[r].w * asv.w;
        float pd = acc[r].x * adv.x + acc[r].y * adv.y + acc[r].z * adv.z + acc[r].w * adv.w;
        ps += __shfl_xor(ps, 1); pd += __shfl_xor(pd, 1);
        ps += __shfl_xor(ps, 2); pd += __shfl_xor(pd, 2);
        ps += __shfl_xor(ps, 4); pd += __shfl_xor(pd, 4);
        if ((lane & 7) == 0) {
            ssrc[gr * NH + (lane >> 3)] = ps;
            sdst[gr * NH + (lane >> 3)] = pd;
        }
    }
}

// ---------------- fused GAT aggregation + bias + BN(eval) + ELU ----------------

template <int OUTH>
__global__ __launch_bounds__(256) void gat_agg(const int* __restrict__ row_ptr,
                                               const int* __restrict__ colidx,
                                               const float* __restrict__ ssrc,
                                               const float* __restrict__ sdst,
                                               const _Float16* __restrict__ h,
                                               const float* __restrict__ bias,
                                               const float* __restrict__ gamma,
                                               const float* __restrict__ beta,
                                               float* __restrict__ out,
                                               _Float16* __restrict__ outh) {
    int wave = (blockIdx.x * blockDim.x + threadIdx.x) >> 6;
    int lane = threadIdx.x & 63;
    if (wave >= N_NODES) return;
    int n = wave;
    int beg = row_ptr[n], end = row_ptr[n + 1];
    int deg = end - beg;

    int hd1 = lane & 7;
    float sd1 = sdst[n * NH + hd1];
    float mx = -3.0e38f;
    for (int i = (lane >> 3); i < deg; i += 8) {
        int s = colidx[beg + i];
        float v = ssrc[s * NH + hd1] + sd1;
        v = (v >= 0.f) ? v : 0.2f * v;
        mx = fmaxf(mx, v);
    }
    mx = fmaxf(mx, __shfl_xor(mx, 8));
    mx = fmaxf(mx, __shfl_xor(mx, 16));
    mx = fmaxf(mx, __shfl_xor(mx, 32));

    int hd2 = lane >> 3;
    float m2 = __shfl(mx, hd2);
    float sd2 = sdst[n * NH + hd2];
    int c = lane * 4;
    float acc0 = 0.f, acc1 = 0.f, acc2 = 0.f, acc3 = 0.f, denom = 0.f;

    int i = 0;
    for (; i + 4 <= deg; i += 4) {
        int s0 = colidx[beg + i];
        int s1 = colidx[beg + i + 1];
        int s2 = colidx[beg + i + 2];
        int s3 = colidx[beg + i + 3];
        float v0 = ssrc[s0 * NH + hd2] + sd2; v0 = (v0 >= 0.f) ? v0 : 0.2f * v0;
        float v1 = ssrc[s1 * NH + hd2] + sd2; v1 = (v1 >= 0.f) ? v1 : 0.2f * v1;
        float v2 = ssrc[s2 * NH + hd2] + sd2; v2 = (v2 >= 0.f) ? v2 : 0.2f * v2;
        float v3 = ssrc[s3 * NH + hd2] + sd2; v3 = (v3 >= 0.f) ? v3 : 0.2f * v3;
        float w0 = __expf(v0 - m2);
        float w1 = __expf(v1 - m2);
        float w2 = __expf(v2 - m2);
        float w3 = __expf(v3 - m2);
        const f16x4 h0 = *reinterpret_cast<const f16x4*>(h + (size_t)s0 * HC + c);
        const f16x4 h1 = *reinterpret_cast<const f16x4*>(h + (size_t)s1 * HC + c);
        const f16x4 h2 = *reinterpret_cast<const f16x4*>(h + (size_t)s2 * HC + c);
        const f16x4 h3 = *reinterpret_cast<const f16x4*>(h + (size_t)s3 * HC + c);
        denom += (w0 + w1) + (w2 + w3);
        acc0 += w0 * (float)h0[0] + w1 * (float)h1[0] + w2 * (float)h2[0] + w3 * (float)h3[0];
        acc1 += w0 * (float)h0[1] + w1 * (float)h1[1] + w2 * (float)h2[1] + w3 * (float)h3[1];
        acc2 += w0 * (float)h0[2] + w1 * (float)h1[2] + w2 * (float)h2[2] + w3 * (float)h3[2];
        acc3 += w0 * (float)h0[3] + w1 * (float)h1[3] + w2 * (float)h2[3] + w3 * (float)h3[3];
    }
    for (; i < deg; ++i) {
        int s = colidx[beg + i];
        float v = ssrc[s * NH + hd2] + sd2;
        v = (v >= 0.f) ? v : 0.2f * v;
        float wgt = __expf(v - m2);
        denom += wgt;
        const f16x4 hv = *reinterpret_cast<const f16x4*>(h + (size_t)s * HC + c);
        acc0 += wgt * (float)hv[0]; acc1 += wgt * (float)hv[1];
        acc2 += wgt * (float)hv[2]; acc3 += wgt * (float)hv[3];
    }
    float inv = 1.0f / denom;
    const float bninv = 0.99999500003749981f;  // 1/sqrt(1+1e-5)
    float vals[4] = {acc0, acc1, acc2, acc3};
    float res[4];
#pragma unroll
    for (int j = 0; j < 4; ++j) {
        float v = vals[j] * inv + bias[c + j];
        v = v * (gamma[c + j] * bninv) + beta[c + j];
        v = (v > 0.f) ? v : (__expf(v) - 1.0f);
        res[j] = v;
    }
    if (OUTH) {
        f16x4 o;
        o[0] = (_Float16)res[0]; o[1] = (_Float16)res[1];
        o[2] = (_Float16)res[2]; o[3] = (_Float16)res[3];
        *(f16x4*)(outh + (size_t)n * HC + c) = o;
    } else {
        float4 o = make_float4(res[0], res[1], res[2], res[3]);
        *reinterpret_cast<float4*>(out + (size_t)n * HC + c) = o;
    }
}

// ---------------- pooling ----------------

__global__ __launch_bounds__(256) void graph_ranges(const int* __restrict__ batch, int* gstart, int* gend) {
    int n = blockIdx.x * 256 + threadIdx.x;
    if (n >= N_NODES) return;
    int b = batch[n];
    if (n == 0) gstart[b] = 0;
    else {
        int pb = batch[n - 1];
        if (pb != b) { gstart[b] = n; gend[pb] = n; }
    }
    if (n == N_NODES - 1) gend[b] = N_NODES;
}

__global__ __launch_bounds__(256) void pool_partial(const float* __restrict__ h,
                                                    const int* __restrict__ gstart,
                                                    const int* __restrict__ gend,
                                                    float* __restrict__ psum,
                                                    float* __restrict__ pmax) {
    int g = blockIdx.x >> 4;
    int c = blockIdx.x & (PCHUNK - 1);
    int t = threadIdx.x;
    int s = gstart[g], e = gend[g];
    int len = e - s;
    int n0 = s + (int)(((long long)len * c) / PCHUNK);
    int n1 = s + (int)(((long long)len * (c + 1)) / PCHUNK);
    float sum = 0.f, mx = -3.0e38f;
    for (int n = n0; n < n1; ++n) {
        float v = h[(size_t)n * HC + t];
        sum += v;
        mx = fmaxf(mx, v);
    }
    psum[(size_t)(g * PCHUNK + c) * HC + t] = sum;
    pmax[(size_t)(g * PCHUNK + c) * HC + t] = mx;
}

// ---------------- MLP head (fused pool-finalize + 3 FC layers) ----------------

__global__ __launch_bounds__(256) void mlp(const float* __restrict__ psum,
                                           const float* __restrict__ pmax,
                                           const int* __restrict__ gstart,
                                           const int* __restrict__ gend,
                                           const float* __restrict__ gsz,
                                           const float* __restrict__ fc1wT, const float* __restrict__ fc1b,
                                           const float* __restrict__ gf1, const float* __restrict__ bf1,
                                           const float* __restrict__ fc2w, const float* __restrict__ fc2b,
                                           const float* __restrict__ gf2, const float* __restrict__ bf2,
                                           const float* __restrict__ fc3w, const float* __restrict__ fc3b,
                                           float* __restrict__ out) {
    __shared__ __align__(16) float pr[514];
    __shared__ float z1[64];
    __shared__ float zz2[8][32];
    __shared__ float z2[32];
    int g = blockIdx.x;
    int t = threadIdx.x;
    const float bninv = 0.99999500003749981f;

    // phase 0: reduce pool partials
    {
        float s = 0.f, m = -3.0e38f;
#pragma unroll
        for (int c = 0; c < PCHUNK; ++c) {
            s += psum[(size_t)(g * PCHUNK + c) * HC + t];
            m = fmaxf(m, pmax[(size_t)(g * PCHUNK + c) * HC + t]);
        }
        float cnt = (float)(gend[g] - gstart[g]);
        pr[t] = s / fmaxf(cnt, 1.f);
        pr[256 + t] = m;
        if (t < 2) pr[512 + t] = gsz[g * 2 + t];
    }
    __syncthreads();

    // phase 1: fc1 (514 x 64): wave wv computes outputs wv*16..wv*16+15
    {
        int wv = t >> 6, lane = t & 63;
        float4 pa = *reinterpret_cast<const float4*>(&pr[lane * 8]);
        float4 pb = *reinterpret_cast<const float4*>(&pr[lane * 8 + 4]);
#pragma unroll 4
        for (int i = 0; i < 16; ++i) {
            int u = wv * 16 + i;
            const float* wrow = fc1wT + u * 520;
            float4 wa = *reinterpret_cast<const float4*>(wrow + lane * 8);
            float4 wb = *reinterpret_cast<const float4*>(wrow + lane * 8 + 4);
            float a = pa.x * wa.x + pa.y * wa.y + pa.z * wa.z + pa.w * wa.w
                    + pb.x * wb.x + pb.y * wb.y + pb.z * wb.z + pb.w * wb.w;
            if (lane == 0) a += pr[512] * wrow[512] + pr[513] * wrow[513];
            a += __shfl_xor(a, 1); a += __shfl_xor(a, 2); a += __shfl_xor(a, 4);
            a += __shfl_xor(a, 8); a += __shfl_xor(a, 16); a += __shfl_xor(a, 32);
            if (lane == 0) {
                a += fc1b[u];
                a = a * (gf1[u] * bninv) + bf1[u];
                z1[u] = fmaxf(a, 0.f);
            }
        }
    }
    __syncthreads();

    // phase 2: fc2 (64 x 32), 8-way k-split
    {
        int u = t & 31, sp = t >> 5;
        float b = 0.f;
#pragma unroll
        for (int k = sp * 8; k < sp * 8 + 8; ++k) b += z1[k] * fc2w[k * 32 + u];
        zz2[sp][u] = b;
    }
    __syncthreads();
    if (t < 32) {
        float b = 0.f;
#pragma unroll
        for (int sp = 0; sp < 8; ++sp) b += zz2[sp][t];
        b += fc2b[t];
        b = b * (gf2[t] * bninv) + bf2[t];
        z2[t] = fmaxf(b, 0.f);
    }
    __syncthreads();

    // phase 3: fc3 (32 x 2)
    if (t < 2) {
        float c = 0.f;
#pragma unroll
        for (int k = 0; k < 32; ++k) c += z2[k] * fc3w[k * 2 + t];
        out[g * 2 + t] = c + fc3b[t];
    }
}

// ---------------- launch ----------------

extern "C" void kernel_launch(void* const* d_in, const int* in_sizes, int n_in,
                              void* d_out, int out_size, void* d_ws, size_t ws_size,
                              hipStream_t stream) {
    const float* x    = (const float*)d_in[0];
    const int*   ei   = (const int*)d_in[1];
    const int*   batch= (const int*)d_in[2];
    const float* gsz  = (const float*)d_in[3];
    const float* W1   = (const float*)d_in[4];
    const float* as1  = (const float*)d_in[5];
    const float* ad1  = (const float*)d_in[6];
    const float* b1   = (const float*)d_in[7];
    const float* g1   = (const float*)d_in[8];
    const float* be1  = (const float*)d_in[9];
    const float* W2   = (const float*)d_in[10];
    const float* as2  = (const float*)d_in[11];
    const float* ad2  = (const float*)d_in[12];
    const float* b2   = (const float*)d_in[13];
    const float* g2   = (const float*)d_in[14];
    const float* be2  = (const float*)d_in[15];
    const float* fc1w = (const float*)d_in[16];
    const float* fc1b = (const float*)d_in[17];
    const float* gf1  = (const float*)d_in[18];
    const float* bf1  = (const float*)d_in[19];
    const float* fc2w = (const float*)d_in[20];
    const float* fc2b = (const float*)d_in[21];
    const float* gf2  = (const float*)d_in[22];
    const float* bf2  = (const float*)d_in[23];
    const float* fc3w = (const float*)d_in[24];
    const float* fc3b = (const float*)d_in[25];
    float* out = (float*)d_out;

    char* w = (char*)d_ws;
    _Float16* h_half   = (_Float16*)w; w += (size_t)N_NODES * HC * 2;   // 10.24 MB
    _Float16* act_half = (_Float16*)w; w += (size_t)N_NODES * HC * 2;   // 10.24 MB
    float* actbuf      = (float*)w;    w += (size_t)N_NODES * HC * 4;   // 20.48 MB (pool in)
    _Float16* Wt       = (_Float16*)w; w += (size_t)HC * HC * 2;        // 128 KB
    float* fc1wT       = (float*)w;    w += (size_t)64 * 520 * 4;       // 133 KB
    float* ssrc        = (float*)w;    w += (size_t)N_NODES * NH * 4;
    float* sdst        = (float*)w;    w += (size_t)N_NODES * NH * 4;
    int* row_ptr  = (int*)w;   w += (size_t)(N_NODES + 1) * 4;
    int* cursor   = (int*)w;   w += (size_t)N_NODES * 4;
    int* cnt      = (int*)w;   w += (size_t)N_NODES * 4;
    int* colidx   = (int*)w;   w += (size_t)(E_EDGES + N_NODES) * 4;
    int* partial  = (int*)w;   w += 64 * 4;
    int* gstart   = (int*)w;   w += 64 * 4;
    int* gend     = (int*)w;   w += 64 * 4;

    // pool partials alias h_half (dead after gat_agg#2)
    float* psum = (float*)h_half;
    float* pmax = psum + (size_t)NG * PCHUNK * HC;

    hipMemsetAsync(gstart, 0, 2 * 64 * 4, stream);

    init_counts<<<79, 256, 0, stream>>>(cnt);
    hist<<<1250, 256, 0, stream>>>(ei, cnt);
    scanA<<<40, 512, 0, stream>>>(cnt, partial);
    scanB<<<1, 64, 0, stream>>>(partial);
    scanC<<<40, 512, 0, stream>>>(cnt, partial, row_ptr, cursor, colidx);
    fill_csr<<<1250, 256, 0, stream>>>(ei, cursor, colidx);
    wconv<<<16, 256, 0, stream>>>(W2, Wt);
    fc1conv<<<129, 256, 0, stream>>>(fc1w, fc1wT);

    gemm41<<<625, 256, 0, stream>>>(x, W1, as1, ad1, h_half, ssrc, sdst);
    gat_agg<1><<<5000, 256, 0, stream>>>(row_ptr, colidx, ssrc, sdst, h_half, b1, g1, be1,
                                         (float*)nullptr, act_half);

    gemm256h<<<625, 256, 0, stream>>>(act_half, Wt, as2, ad2, h_half, ssrc, sdst);
    gat_agg<0><<<5000, 256, 0, stream>>>(row_ptr, colidx, ssrc, sdst, h_half, b2, g2, be2,
                                         actbuf, (_Float16*)nullptr);

    graph_ranges<<<79, 256, 0, stream>>>(batch, gstart, gend);
    pool_partial<<<NG * PCHUNK, 256, 0, stream>>>(actbuf, gstart, gend, psum, pmax);
    mlp<<<NG, 256, 0, stream>>>(psum, pmax, gstart, gend, gsz,
                                fc1wT, fc1b, gf1, bf1, fc2w, fc2b, gf2, bf2, fc3w, fc3b, out);
}

// Round 10
// 193.315 us; speedup vs baseline: 1.2045x; 1.0003x over previous
//
#include <hip/hip_runtime.h>
#include <hip/hip_bf16.h>

#define N_NODES 20000
#define E_EDGES 320000
#define NH 8
#define NC 32
#define HC 256
#define FIN 41
#define NG 64
#define PCHUNK 16

typedef _Float16 f16x4 __attribute__((ext_vector_type(4)));
typedef _Float16 f16x8 __attribute__((ext_vector_type(8)));
typedef float f32x4v __attribute__((ext_vector_type(4)));

// ---------------- CSR build ----------------

__global__ __launch_bounds__(256) void init_counts(int* cnt) {
    int n = blockIdx.x * 256 + threadIdx.x;
    if (n < N_NODES) cnt[n] = 1;  // self loop
}

__global__ __launch_bounds__(256) void hist(const int* __restrict__ ei, int* cnt) {
    int e = blockIdx.x * 256 + threadIdx.x;
    if (e < E_EDGES) atomicAdd(&cnt[ei[E_EDGES + e]], 1);
}

__global__ __launch_bounds__(512) void scanA(const int* __restrict__ cnt, int* partial) {
    __shared__ int red[512];
    int n = blockIdx.x * 512 + threadIdx.x;
    int v = (n < N_NODES) ? cnt[n] : 0;
    red[threadIdx.x] = v; __syncthreads();
    for (int off = 256; off > 0; off >>= 1) {
        if (threadIdx.x < off) red[threadIdx.x] += red[threadIdx.x + off];
        __syncthreads();
    }
    if (threadIdx.x == 0) partial[blockIdx.x] = red[0];
}

__global__ __launch_bounds__(64) void scanB(int* partial) {
    int t = threadIdx.x;
    int v = (t < 40) ? partial[t] : 0;
    int orig = v;
    for (int off = 1; off < 64; off <<= 1) {
        int y = __shfl_up(v, off);
        if (t >= off) v += y;
    }
    if (t < 40) partial[t] = v - orig;  // exclusive
}

__global__ __launch_bounds__(512) void scanC(const int* __restrict__ cnt, const int* __restrict__ partial,
                                             int* row_ptr, int* cursor, int* colidx) {
    __shared__ int buf[512];
    int t = threadIdx.x;
    int n = blockIdx.x * 512 + t;
    int v = (n < N_NODES) ? cnt[n] : 0;
    int x = v;
    buf[t] = x; __syncthreads();
    for (int off = 1; off < 512; off <<= 1) {
        int y = (t >= off) ? buf[t - off] : 0;
        __syncthreads();
        x += y; buf[t] = x; __syncthreads();
    }
    int excl = partial[blockIdx.x] + x - v;
    if (n < N_NODES) {
        row_ptr[n] = excl;
        cursor[n] = excl + 1;     // self loop occupies slot 0
        colidx[excl] = n;         // self loop
    }
    if (n == 0) row_ptr[N_NODES] = E_EDGES + N_NODES;
}

__global__ __launch_bounds__(256) void fill_csr(const int* __restrict__ ei, int* cursor, int* colidx) {
    int e = blockIdx.x * 256 + threadIdx.x;
    if (e >= E_EDGES) return;
    int d = ei[E_EDGES + e];
    int s = ei[e];
    int pos = atomicAdd(&cursor[d], 1);
    colidx[pos] = s;
}

// ---------------- W2 -> fp16 col-major via LDS tile transpose ----------------

__global__ __launch_bounds__(256) void wconv(const float* __restrict__ W, _Float16* __restrict__ Wt) {
    __shared__ float tile[64][65];
    int tr = (blockIdx.x >> 2) * 64;   // k-range
    int tc = (blockIdx.x & 3) * 64;    // n-range
    int t = threadIdx.x;
    int rr = t >> 6, cc = t & 63;
#pragma unroll
    for (int j = 0; j < 16; ++j) {
        int row = j * 4 + rr;
        tile[row][cc] = W[(size_t)(tr + row) * 256 + tc + cc];
    }
    __syncthreads();
#pragma unroll
    for (int j = 0; j < 16; ++j) {
        int row = j * 4 + rr;  // n-offset
        Wt[(size_t)(tc + row) * 256 + tr + cc] = (_Float16)tile[cc][row];
    }
}

// ---------------- fc1w [514][64] -> fc1wT [64][520] (row-padded) ----------------

__global__ __launch_bounds__(256) void fc1conv(const float* __restrict__ fc1w, float* __restrict__ fc1wT) {
    int id = blockIdx.x * 256 + threadIdx.x;
    if (id >= 64 * 514) return;
    int u = id / 514, kk = id - u * 514;
    fc1wT[u * 520 + kk] = fc1w[kk * 64 + u];
}

// ---------------- GEMM K=256 via MFMA fp16 (16x16x32) + fused score dots ----------------
// block = 32 rows x 256 cols, 4 waves; wave w: cols [w*64, w*64+64) = heads 2w,2w+1.
// K-steps of 32: per-lane f16x8 (16B) fragments, 8 steps, 2-deep register pipeline.

__global__ __launch_bounds__(256) void gemm256h(const _Float16* __restrict__ Xh,
                                                const _Float16* __restrict__ Wt,
                                                const float* __restrict__ a_src,
                                                const float* __restrict__ a_dst,
                                                _Float16* __restrict__ Hh,
                                                float* __restrict__ ssrc,
                                                float* __restrict__ sdst) {
    __shared__ _Float16 hs[32 * 264];
    int row0 = blockIdx.x * 32;
    int tid = threadIdx.x;
    int lane = tid & 63;
    int w = tid >> 6;
    int r16 = lane & 15;
    int kseg = lane >> 4;

    f32x4v acc[2][4];
#pragma unroll
    for (int a = 0; a < 2; ++a)
#pragma unroll
        for (int b = 0; b < 4; ++b) acc[a][b] = (f32x4v){0.f, 0.f, 0.f, 0.f};

    const _Float16* XA = Xh + (size_t)(row0 + r16) * 256 + kseg * 8;
    const _Float16* WB = Wt + (size_t)(w * 64 + r16) * 256 + kseg * 8;

    f16x8 a0[2], a1[2], b0[2], b1[2], b2[2], b3[2];
#define LOADF(st, koff)                                   \
    a0[st] = *(const f16x8*)(XA + (koff));                \
    a1[st] = *(const f16x8*)(XA + 16 * 256 + (koff));     \
    b0[st] = *(const f16x8*)(WB + (koff));                \
    b1[st] = *(const f16x8*)(WB + 16 * 256 + (koff));     \
    b2[st] = *(const f16x8*)(WB + 32 * 256 + (koff));     \
    b3[st] = *(const f16x8*)(WB + 48 * 256 + (koff));

    LOADF(0, 0)
#pragma unroll
    for (int s = 0; s < 8; ++s) {
        const int cur = s & 1, nxt = cur ^ 1;
        if (s < 7) { LOADF(nxt, (s + 1) * 32) }
        acc[0][0] = __builtin_amdgcn_mfma_f32_16x16x32_f16(a0[cur], b0[cur], acc[0][0], 0, 0, 0);
        acc[0][1] = __builtin_amdgcn_mfma_f32_16x16x32_f16(a0[cur], b1[cur], acc[0][1], 0, 0, 0);
        acc[0][2] = __builtin_amdgcn_mfma_f32_16x16x32_f16(a0[cur], b2[cur], acc[0][2], 0, 0, 0);
        acc[0][3] = __builtin_amdgcn_mfma_f32_16x16x32_f16(a0[cur], b3[cur], acc[0][3], 0, 0, 0);
        acc[1][0] = __builtin_amdgcn_mfma_f32_16x16x32_f16(a1[cur], b0[cur], acc[1][0], 0, 0, 0);
        acc[1][1] = __builtin_amdgcn_mfma_f32_16x16x32_f16(a1[cur], b1[cur], acc[1][1], 0, 0, 0);
        acc[1][2] = __builtin_amdgcn_mfma_f32_16x16x32_f16(a1[cur], b2[cur], acc[1][2], 0, 0, 0);
        acc[1][3] = __builtin_amdgcn_mfma_f32_16x16x32_f16(a1[cur], b3[cur], acc[1][3], 0, 0, 0);
    }
#undef LOADF

    // fused attention-score dots: wave w's 64 cols = heads 2w, 2w+1 complete
    float as0 = a_src[w * 64 + r16],      as1 = a_src[w * 64 + 16 + r16];
    float as2 = a_src[w * 64 + 32 + r16], as3 = a_src[w * 64 + 48 + r16];
    float ad0 = a_dst[w * 64 + r16],      ad1 = a_dst[w * 64 + 16 + r16];
    float ad2 = a_dst[w * 64 + 32 + r16], ad3 = a_dst[w * 64 + 48 + r16];
#pragma unroll
    for (int tm = 0; tm < 2; ++tm) {
#pragma unroll
        for (int r = 0; r < 4; ++r) {
            float p0 = acc[tm][0][r] * as0 + acc[tm][1][r] * as1;
            float p1 = acc[tm][2][r] * as2 + acc[tm][3][r] * as3;
            float q0 = acc[tm][0][r] * ad0 + acc[tm][1][r] * ad1;
            float q1 = acc[tm][2][r] * ad2 + acc[tm][3][r] * ad3;
#pragma unroll
            for (int m = 1; m < 16; m <<= 1) {
                p0 += __shfl_xor(p0, m); p1 += __shfl_xor(p1, m);
                q0 += __shfl_xor(q0, m); q1 += __shfl_xor(q1, m);
            }
            if (r16 == 0) {
                int row = row0 + tm * 16 + kseg * 4 + r;
                ssrc[row * NH + w * 2]     = p0;
                ssrc[row * NH + w * 2 + 1] = p1;
                sdst[row * NH + w * 2]     = q0;
                sdst[row * NH + w * 2 + 1] = q1;
            }
        }
    }

    // H (fp16) via LDS transpose for coalesced 16B stores
#pragma unroll
    for (int tm = 0; tm < 2; ++tm)
#pragma unroll
        for (int tn = 0; tn < 4; ++tn)
#pragma unroll
            for (int r = 0; r < 4; ++r)
                hs[(tm * 16 + kseg * 4 + r) * 264 + w * 64 + tn * 16 + r16] = (_Float16)acc[tm][tn][r];
    __syncthreads();
#pragma unroll
    for (int i = 0; i < 4; ++i) {
        int idx = i * 256 + tid;
        int rr = idx >> 5;
        int cc = idx & 31;
        f16x8 v = *(const f16x8*)&hs[rr * 264 + cc * 8];
        *(f16x8*)(Hh + (size_t)(row0 + rr) * 256 + cc * 8) = v;
    }
}

// ---------------- GEMM K=41 (fp32 VALU) + fused score dots, fp16 H out ----------------

__global__ __launch_bounds__(256) void gemm41(const float* __restrict__ X,
                                              const float* __restrict__ W,
                                              const float* __restrict__ a_src,
                                              const float* __restrict__ a_dst,
                                              _Float16* __restrict__ Hh,
                                              float* __restrict__ ssrc,
                                              float* __restrict__ sdst) {
    __shared__ float xs[32][44];
    int row0 = blockIdx.x * 32;
    int tid = threadIdx.x;
    int lane = tid & 63;
    int wave = tid >> 6;
    int c4 = lane * 4;
    int wrow = wave * 8;

    for (int idx = tid; idx < 32 * FIN; idx += 256) {
        int r = idx / FIN, k = idx - r * FIN;
        xs[r][k] = X[(size_t)(row0 + r) * FIN + k];
    }
    __syncthreads();

    float4 acc[8];
#pragma unroll
    for (int r = 0; r < 8; ++r) acc[r] = make_float4(0.f, 0.f, 0.f, 0.f);

    for (int k = 0; k < FIN; ++k) {
        float4 w0 = *reinterpret_cast<const float4*>(W + (size_t)k * HC + c4);
#pragma unroll
        for (int r = 0; r < 8; ++r) {
            float xv = xs[wrow + r][k];
            acc[r].x += xv * w0.x; acc[r].y += xv * w0.y; acc[r].z += xv * w0.z; acc[r].w += xv * w0.w;
        }
    }
    const float4 asv = *reinterpret_cast<const float4*>(a_src + c4);
    const float4 adv = *reinterpret_cast<const float4*>(a_dst + c4);
#pragma unroll
    for (int r = 0; r < 8; ++r) {
        int gr = row0 + wrow + r;
        f16x4 hv;
        hv[0] = (_Float16)acc[r].x; hv[1] = (_Float16)acc[r].y;
        hv[2] = (_Float16)acc[r].z; hv[3] = (_Float16)acc[r].w;
        *(f16x4*)(Hh + (size_t)gr * HC + c4) = hv;
        float ps = acc[r].x * asv.x + acc[r].y * asv.y + acc[r].z * asv.z + acc[r].w * asv.w;
        float pd = acc[r].x * adv.x + acc[r].y * adv.y + acc[r].z * adv.z + acc[r].w * adv.w;
        ps += __shfl_xor(ps, 1); pd += __shfl_xor(pd, 1);
        ps += __shfl_xor(ps, 2); pd += __shfl_xor(pd, 2);
        ps += __shfl_xor(ps, 4); pd += __shfl_xor(pd, 4);
        if ((lane & 7) == 0) {
            ssrc[gr * NH + (lane >> 3)] = ps;
            sdst[gr * NH + (lane >> 3)] = pd;
        }
    }
}

// ---------------- fused GAT aggregation + bias + BN(eval) + ELU ----------------
// one wave per dst node; lane owns 4 channels; phase-2 batched 8x unroll:
// 8 colidx -> 8 score gathers -> 8 h-row loads (8 independent 512B gather chains).
// fp16 output always.

__global__ __launch_bounds__(256) void gat_agg(const int* __restrict__ row_ptr,
                                               const int* __restrict__ colidx,
                                               const float* __restrict__ ssrc,
                                               const float* __restrict__ sdst,
                                               const _Float16* __restrict__ h,
                                               const float* __restrict__ bias,
                                               const float* __restrict__ gamma,
                                               const float* __restrict__ beta,
                                               _Float16* __restrict__ outh) {
    int wave = (blockIdx.x * blockDim.x + threadIdx.x) >> 6;
    int lane = threadIdx.x & 63;
    if (wave >= N_NODES) return;
    int n = wave;
    int beg = row_ptr[n], end = row_ptr[n + 1];
    int deg = end - beg;

    int hd1 = lane & 7;
    float sd1 = sdst[n * NH + hd1];
    float mx = -3.0e38f;
    for (int i = (lane >> 3); i < deg; i += 8) {
        int s = colidx[beg + i];
        float v = ssrc[s * NH + hd1] + sd1;
        v = (v >= 0.f) ? v : 0.2f * v;
        mx = fmaxf(mx, v);
    }
    mx = fmaxf(mx, __shfl_xor(mx, 8));
    mx = fmaxf(mx, __shfl_xor(mx, 16));
    mx = fmaxf(mx, __shfl_xor(mx, 32));

    int hd2 = lane >> 3;
    float m2 = __shfl(mx, hd2);
    float sd2 = sdst[n * NH + hd2];
    int c = lane * 4;
    float acc0 = 0.f, acc1 = 0.f, acc2 = 0.f, acc3 = 0.f, denom = 0.f;

    int i = 0;
    for (; i + 8 <= deg; i += 8) {
        int sidx[8];
#pragma unroll
        for (int j = 0; j < 8; ++j) sidx[j] = colidx[beg + i + j];
        float wv[8];
#pragma unroll
        for (int j = 0; j < 8; ++j) {
            float v = ssrc[sidx[j] * NH + hd2] + sd2;
            v = (v >= 0.f) ? v : 0.2f * v;
            wv[j] = __expf(v - m2);
        }
        f16x4 hv[8];
#pragma unroll
        for (int j = 0; j < 8; ++j) hv[j] = *reinterpret_cast<const f16x4*>(h + (size_t)sidx[j] * HC + c);
#pragma unroll
        for (int j = 0; j < 8; ++j) {
            denom += wv[j];
            acc0 += wv[j] * (float)hv[j][0];
            acc1 += wv[j] * (float)hv[j][1];
            acc2 += wv[j] * (float)hv[j][2];
            acc3 += wv[j] * (float)hv[j][3];
        }
    }
    for (; i < deg; ++i) {
        int s = colidx[beg + i];
        float v = ssrc[s * NH + hd2] + sd2;
        v = (v >= 0.f) ? v : 0.2f * v;
        float wgt = __expf(v - m2);
        denom += wgt;
        const f16x4 hv = *reinterpret_cast<const f16x4*>(h + (size_t)s * HC + c);
        acc0 += wgt * (float)hv[0]; acc1 += wgt * (float)hv[1];
        acc2 += wgt * (float)hv[2]; acc3 += wgt * (float)hv[3];
    }
    float inv = 1.0f / denom;
    const float bninv = 0.99999500003749981f;  // 1/sqrt(1+1e-5)
    float vals[4] = {acc0, acc1, acc2, acc3};
    f16x4 o;
#pragma unroll
    for (int j = 0; j < 4; ++j) {
        float v = vals[j] * inv + bias[c + j];
        v = v * (gamma[c + j] * bninv) + beta[c + j];
        v = (v > 0.f) ? v : (__expf(v) - 1.0f);
        o[j] = (_Float16)v;
    }
    *(f16x4*)(outh + (size_t)n * HC + c) = o;
}

// ---------------- pooling ----------------

__global__ __launch_bounds__(256) void graph_ranges(const int* __restrict__ batch, int* gstart, int* gend) {
    int n = blockIdx.x * 256 + threadIdx.x;
    if (n >= N_NODES) return;
    int b = batch[n];
    if (n == 0) gstart[b] = 0;
    else {
        int pb = batch[n - 1];
        if (pb != b) { gstart[b] = n; gend[pb] = n; }
    }
    if (n == N_NODES - 1) gend[b] = N_NODES;
}

__global__ __launch_bounds__(256) void pool_partial(const _Float16* __restrict__ h,
                                                    const int* __restrict__ gstart,
                                                    const int* __restrict__ gend,
                                                    float* __restrict__ psum,
                                                    float* __restrict__ pmax) {
    int g = blockIdx.x >> 4;
    int c = blockIdx.x & (PCHUNK - 1);
    int t = threadIdx.x;
    int s = gstart[g], e = gend[g];
    int len = e - s;
    int n0 = s + (int)(((long long)len * c) / PCHUNK);
    int n1 = s + (int)(((long long)len * (c + 1)) / PCHUNK);
    float sum = 0.f, mx = -3.0e38f;
    for (int n = n0; n < n1; ++n) {
        float v = (float)h[(size_t)n * HC + t];
        sum += v;
        mx = fmaxf(mx, v);
    }
    psum[(size_t)(g * PCHUNK + c) * HC + t] = sum;
    pmax[(size_t)(g * PCHUNK + c) * HC + t] = mx;
}

// ---------------- MLP head (fused pool-finalize + 3 FC layers) ----------------

__global__ __launch_bounds__(256) void mlp(const float* __restrict__ psum,
                                           const float* __restrict__ pmax,
                                           const int* __restrict__ gstart,
                                           const int* __restrict__ gend,
                                           const float* __restrict__ gsz,
                                           const float* __restrict__ fc1wT, const float* __restrict__ fc1b,
                                           const float* __restrict__ gf1, const float* __restrict__ bf1,
                                           const float* __restrict__ fc2w, const float* __restrict__ fc2b,
                                           const float* __restrict__ gf2, const float* __restrict__ bf2,
                                           const float* __restrict__ fc3w, const float* __restrict__ fc3b,
                                           float* __restrict__ out) {
    __shared__ __align__(16) float pr[514];
    __shared__ float z1[64];
    __shared__ float zz2[8][32];
    __shared__ float z2[32];
    int g = blockIdx.x;
    int t = threadIdx.x;
    const float bninv = 0.99999500003749981f;

    // phase 0: reduce pool partials
    {
        float s = 0.f, m = -3.0e38f;
#pragma unroll
        for (int c = 0; c < PCHUNK; ++c) {
            s += psum[(size_t)(g * PCHUNK + c) * HC + t];
            m = fmaxf(m, pmax[(size_t)(g * PCHUNK + c) * HC + t]);
        }
        float cnt = (float)(gend[g] - gstart[g]);
        pr[t] = s / fmaxf(cnt, 1.f);
        pr[256 + t] = m;
        if (t < 2) pr[512 + t] = gsz[g * 2 + t];
    }
    __syncthreads();

    // phase 1: fc1 (514 x 64): wave wv computes outputs wv*16..wv*16+15
    {
        int wv = t >> 6, lane = t & 63;
        float4 pa = *reinterpret_cast<const float4*>(&pr[lane * 8]);
        float4 pb = *reinterpret_cast<const float4*>(&pr[lane * 8 + 4]);
#pragma unroll 4
        for (int i = 0; i < 16; ++i) {
            int u = wv * 16 + i;
            const float* wrow = fc1wT + u * 520;
            float4 wa = *reinterpret_cast<const float4*>(wrow + lane * 8);
            float4 wb = *reinterpret_cast<const float4*>(wrow + lane * 8 + 4);
            float a = pa.x * wa.x + pa.y * wa.y + pa.z * wa.z + pa.w * wa.w
                    + pb.x * wb.x + pb.y * wb.y + pb.z * wb.z + pb.w * wb.w;
            if (lane == 0) a += pr[512] * wrow[512] + pr[513] * wrow[513];
            a += __shfl_xor(a, 1); a += __shfl_xor(a, 2); a += __shfl_xor(a, 4);
            a += __shfl_xor(a, 8); a += __shfl_xor(a, 16); a += __shfl_xor(a, 32);
            if (lane == 0) {
                a += fc1b[u];
                a = a * (gf1[u] * bninv) + bf1[u];
                z1[u] = fmaxf(a, 0.f);
            }
        }
    }
    __syncthreads();

    // phase 2: fc2 (64 x 32), 8-way k-split
    {
        int u = t & 31, sp = t >> 5;
        float b = 0.f;
#pragma unroll
        for (int k = sp * 8; k < sp * 8 + 8; ++k) b += z1[k] * fc2w[k * 32 + u];
        zz2[sp][u] = b;
    }
    __syncthreads();
    if (t < 32) {
        float b = 0.f;
#pragma unroll
        for (int sp = 0; sp < 8; ++sp) b += zz2[sp][t];
        b += fc2b[t];
        b = b * (gf2[t] * bninv) + bf2[t];
        z2[t] = fmaxf(b, 0.f);
    }
    __syncthreads();

    // phase 3: fc3 (32 x 2)
    if (t < 2) {
        float c = 0.f;
#pragma unroll
        for (int k = 0; k < 32; ++k) c += z2[k] * fc3w[k * 2 + t];
        out[g * 2 + t] = c + fc3b[t];
    }
}

// ---------------- launch ----------------

extern "C" void kernel_launch(void* const* d_in, const int* in_sizes, int n_in,
                              void* d_out, int out_size, void* d_ws, size_t ws_size,
                              hipStream_t stream) {
    const float* x    = (const float*)d_in[0];
    const int*   ei   = (const int*)d_in[1];
    const int*   batch= (const int*)d_in[2];
    const float* gsz  = (const float*)d_in[3];
    const float* W1   = (const float*)d_in[4];
    const float* as1  = (const float*)d_in[5];
    const float* ad1  = (const float*)d_in[6];
    const float* b1   = (const float*)d_in[7];
    const float* g1   = (const float*)d_in[8];
    const float* be1  = (const float*)d_in[9];
    const float* W2   = (const float*)d_in[10];
    const float* as2  = (const float*)d_in[11];
    const float* ad2  = (const float*)d_in[12];
    const float* b2   = (const float*)d_in[13];
    const float* g2   = (const float*)d_in[14];
    const float* be2  = (const float*)d_in[15];
    const float* fc1w = (const float*)d_in[16];
    const float* fc1b = (const float*)d_in[17];
    const float* gf1  = (const float*)d_in[18];
    const float* bf1  = (const float*)d_in[19];
    const float* fc2w = (const float*)d_in[20];
    const float* fc2b = (const float*)d_in[21];
    const float* gf2  = (const float*)d_in[22];
    const float* bf2  = (const float*)d_in[23];
    const float* fc3w = (const float*)d_in[24];
    const float* fc3b = (const float*)d_in[25];
    float* out = (float*)d_out;

    char* w = (char*)d_ws;
    _Float16* h_half   = (_Float16*)w; w += (size_t)N_NODES * HC * 2;   // 10.24 MB
    _Float16* act_half = (_Float16*)w; w += (size_t)N_NODES * HC * 2;   // 10.24 MB
    _Float16* act2_half= (_Float16*)w; w += (size_t)N_NODES * HC * 2;   // 10.24 MB
    _Float16* Wt       = (_Float16*)w; w += (size_t)HC * HC * 2;        // 128 KB
    float* fc1wT       = (float*)w;    w += (size_t)64 * 520 * 4;       // 133 KB
    float* ssrc        = (float*)w;    w += (size_t)N_NODES * NH * 4;
    float* sdst        = (float*)w;    w += (size_t)N_NODES * NH * 4;
    int* row_ptr  = (int*)w;   w += (size_t)(N_NODES + 1) * 4;
    int* cursor   = (int*)w;   w += (size_t)N_NODES * 4;
    int* cnt      = (int*)w;   w += (size_t)N_NODES * 4;
    int* colidx   = (int*)w;   w += (size_t)(E_EDGES + N_NODES) * 4;
    int* partial  = (int*)w;   w += 64 * 4;
    int* gstart   = (int*)w;   w += 64 * 4;
    int* gend     = (int*)w;   w += 64 * 4;

    // pool partials alias h_half (dead after gat_agg#2)
    float* psum = (float*)h_half;
    float* pmax = psum + (size_t)NG * PCHUNK * HC;

    hipMemsetAsync(gstart, 0, 2 * 64 * 4, stream);

    init_counts<<<79, 256, 0, stream>>>(cnt);
    hist<<<1250, 256, 0, stream>>>(ei, cnt);
    scanA<<<40, 512, 0, stream>>>(cnt, partial);
    scanB<<<1, 64, 0, stream>>>(partial);
    scanC<<<40, 512, 0, stream>>>(cnt, partial, row_ptr, cursor, colidx);
    fill_csr<<<1250, 256, 0, stream>>>(ei, cursor, colidx);
    wconv<<<16, 256, 0, stream>>>(W2, Wt);
    fc1conv<<<129, 256, 0, stream>>>(fc1w, fc1wT);

    gemm41<<<625, 256, 0, stream>>>(x, W1, as1, ad1, h_half, ssrc, sdst);
    gat_agg<<<5000, 256, 0, stream>>>(row_ptr, colidx, ssrc, sdst, h_half, b1, g1, be1, act_half);

    gemm256h<<<625, 256, 0, stream>>>(act_half, Wt, as2, ad2, h_half, ssrc, sdst);
    gat_agg<<<5000, 256, 0, stream>>>(row_ptr, colidx, ssrc, sdst, h_half, b2, g2, be2, act2_half);

    graph_ranges<<<79, 256, 0, stream>>>(batch, gstart, gend);
    pool_partial<<<NG * PCHUNK, 256, 0, stream>>>(act2_half, gstart, gend, psum, pmax);
    mlp<<<NG, 256, 0, stream>>>(psum, pmax, gstart, gend, gsz,
                                fc1wT, fc1b, gf1, bf1, fc2w, fc2b, gf2, bf2, fc3w, fc3b, out);
}

// Round 11
// 179.482 us; speedup vs baseline: 1.2974x; 1.0771x over previous
//
#include <hip/hip_runtime.h>
#include <hip/hip_bf16.h>

#define N_NODES 20000
#define E_EDGES 320000
#define NH 8
#define NC 32
#define HC 256
#define FIN 41
#define NG 64
#define PCHUNK 16

typedef _Float16 f16x4 __attribute__((ext_vector_type(4)));
typedef _Float16 f16x8 __attribute__((ext_vector_type(8)));
typedef float f32x4v __attribute__((ext_vector_type(4)));

// ---------------- CSR build ----------------
// cnt[] holds EDGE counts only (zeroed by memset); row size = cnt[n] + 1 (self loop).

__global__ __launch_bounds__(256) void hist(const int* __restrict__ ei, int* cnt) {
    int e = blockIdx.x * 256 + threadIdx.x;
    if (e < E_EDGES) atomicAdd(&cnt[ei[E_EDGES + e]], 1);
}

__global__ __launch_bounds__(512) void scanA(const int* __restrict__ cnt, int* partial) {
    __shared__ int red[512];
    int n = blockIdx.x * 512 + threadIdx.x;
    int v = (n < N_NODES) ? cnt[n] + 1 : 0;
    red[threadIdx.x] = v; __syncthreads();
    for (int off = 256; off > 0; off >>= 1) {
        if (threadIdx.x < off) red[threadIdx.x] += red[threadIdx.x + off];
        __syncthreads();
    }
    if (threadIdx.x == 0) partial[blockIdx.x] = red[0];
}

__global__ __launch_bounds__(64) void scanB(int* partial) {
    int t = threadIdx.x;
    int v = (t < 40) ? partial[t] : 0;
    int orig = v;
    for (int off = 1; off < 64; off <<= 1) {
        int y = __shfl_up(v, off);
        if (t >= off) v += y;
    }
    if (t < 40) partial[t] = v - orig;  // exclusive
}

__global__ __launch_bounds__(512) void scanC(const int* __restrict__ cnt, const int* __restrict__ partial,
                                             int* row_ptr, int* cursor, int* colidx) {
    __shared__ int buf[512];
    int t = threadIdx.x;
    int n = blockIdx.x * 512 + t;
    int v = (n < N_NODES) ? cnt[n] + 1 : 0;
    int x = v;
    buf[t] = x; __syncthreads();
    for (int off = 1; off < 512; off <<= 1) {
        int y = (t >= off) ? buf[t - off] : 0;
        __syncthreads();
        x += y; buf[t] = x; __syncthreads();
    }
    int excl = partial[blockIdx.x] + x - v;
    if (n < N_NODES) {
        row_ptr[n] = excl;
        cursor[n] = excl + 1;     // self loop occupies slot 0
        colidx[excl] = n;         // self loop
    }
    if (n == 0) row_ptr[N_NODES] = E_EDGES + N_NODES;
}

__global__ __launch_bounds__(256) void fill_csr(const int* __restrict__ ei, int* cursor, int* colidx) {
    int e = blockIdx.x * 256 + threadIdx.x;
    if (e >= E_EDGES) return;
    int d = ei[E_EDGES + e];
    int s = ei[e];
    int pos = atomicAdd(&cursor[d], 1);
    colidx[pos] = s;
}

// ---------------- prep: wconv (blocks 0..15) + fc1conv (16..144) + graph_ranges (145..223) ----------------

__global__ __launch_bounds__(256) void prep(const float* __restrict__ W, _Float16* __restrict__ Wt,
                                            const float* __restrict__ fc1w, float* __restrict__ fc1wT,
                                            const int* __restrict__ batch, int* gstart, int* gend) {
    __shared__ float tile[64][65];
    int b = blockIdx.x;
    int t = threadIdx.x;
    if (b < 16) {
        // W2 [256][256] -> fp16 col-major Wt[n][k]
        int tr = (b >> 2) * 64;
        int tc = (b & 3) * 64;
        int rr = t >> 6, cc = t & 63;
#pragma unroll
        for (int j = 0; j < 16; ++j) {
            int row = j * 4 + rr;
            tile[row][cc] = W[(size_t)(tr + row) * 256 + tc + cc];
        }
        __syncthreads();
#pragma unroll
        for (int j = 0; j < 16; ++j) {
            int row = j * 4 + rr;
            Wt[(size_t)(tc + row) * 256 + tr + cc] = (_Float16)tile[cc][row];
        }
    } else if (b < 145) {
        int id = (b - 16) * 256 + t;
        if (id < 64 * 514) {
            int u = id / 514, kk = id - u * 514;
            fc1wT[u * 520 + kk] = fc1w[kk * 64 + u];
        }
    } else {
        int n = (b - 145) * 256 + t;
        if (n < N_NODES) {
            int bb = batch[n];
            if (n == 0) gstart[bb] = 0;
            else {
                int pb = batch[n - 1];
                if (pb != bb) { gstart[bb] = n; gend[pb] = n; }
            }
            if (n == N_NODES - 1) gend[bb] = N_NODES;
        }
    }
}

// ---------------- GEMM K=256 via MFMA fp16 (16x16x32) + fused score dots ----------------

__global__ __launch_bounds__(256) void gemm256h(const _Float16* __restrict__ Xh,
                                                const _Float16* __restrict__ Wt,
                                                const float* __restrict__ a_src,
                                                const float* __restrict__ a_dst,
                                                _Float16* __restrict__ Hh,
                                                float* __restrict__ ssrc,
                                                float* __restrict__ sdst) {
    __shared__ _Float16 hs[32 * 264];
    int row0 = blockIdx.x * 32;
    int tid = threadIdx.x;
    int lane = tid & 63;
    int w = tid >> 6;
    int r16 = lane & 15;
    int kseg = lane >> 4;

    f32x4v acc[2][4];
#pragma unroll
    for (int a = 0; a < 2; ++a)
#pragma unroll
        for (int b = 0; b < 4; ++b) acc[a][b] = (f32x4v){0.f, 0.f, 0.f, 0.f};

    const _Float16* XA = Xh + (size_t)(row0 + r16) * 256 + kseg * 8;
    const _Float16* WB = Wt + (size_t)(w * 64 + r16) * 256 + kseg * 8;

    f16x8 a0[2], a1[2], b0[2], b1[2], b2[2], b3[2];
#define LOADF(st, koff)                                   \
    a0[st] = *(const f16x8*)(XA + (koff));                \
    a1[st] = *(const f16x8*)(XA + 16 * 256 + (koff));     \
    b0[st] = *(const f16x8*)(WB + (koff));                \
    b1[st] = *(const f16x8*)(WB + 16 * 256 + (koff));     \
    b2[st] = *(const f16x8*)(WB + 32 * 256 + (koff));     \
    b3[st] = *(const f16x8*)(WB + 48 * 256 + (koff));

    LOADF(0, 0)
#pragma unroll
    for (int s = 0; s < 8; ++s) {
        const int cur = s & 1, nxt = cur ^ 1;
        if (s < 7) { LOADF(nxt, (s + 1) * 32) }
        acc[0][0] = __builtin_amdgcn_mfma_f32_16x16x32_f16(a0[cur], b0[cur], acc[0][0], 0, 0, 0);
        acc[0][1] = __builtin_amdgcn_mfma_f32_16x16x32_f16(a0[cur], b1[cur], acc[0][1], 0, 0, 0);
        acc[0][2] = __builtin_amdgcn_mfma_f32_16x16x32_f16(a0[cur], b2[cur], acc[0][2], 0, 0, 0);
        acc[0][3] = __builtin_amdgcn_mfma_f32_16x16x32_f16(a0[cur], b3[cur], acc[0][3], 0, 0, 0);
        acc[1][0] = __builtin_amdgcn_mfma_f32_16x16x32_f16(a1[cur], b0[cur], acc[1][0], 0, 0, 0);
        acc[1][1] = __builtin_amdgcn_mfma_f32_16x16x32_f16(a1[cur], b1[cur], acc[1][1], 0, 0, 0);
        acc[1][2] = __builtin_amdgcn_mfma_f32_16x16x32_f16(a1[cur], b2[cur], acc[1][2], 0, 0, 0);
        acc[1][3] = __builtin_amdgcn_mfma_f32_16x16x32_f16(a1[cur], b3[cur], acc[1][3], 0, 0, 0);
    }
#undef LOADF

    float as0 = a_src[w * 64 + r16],      as1 = a_src[w * 64 + 16 + r16];
    float as2 = a_src[w * 64 + 32 + r16], as3 = a_src[w * 64 + 48 + r16];
    float ad0 = a_dst[w * 64 + r16],      ad1 = a_dst[w * 64 + 16 + r16];
    float ad2 = a_dst[w * 64 + 32 + r16], ad3 = a_dst[w * 64 + 48 + r16];
#pragma unroll
    for (int tm = 0; tm < 2; ++tm) {
#pragma unroll
        for (int r = 0; r < 4; ++r) {
            float p0 = acc[tm][0][r] * as0 + acc[tm][1][r] * as1;
            float p1 = acc[tm][2][r] * as2 + acc[tm][3][r] * as3;
            float q0 = acc[tm][0][r] * ad0 + acc[tm][1][r] * ad1;
            float q1 = acc[tm][2][r] * ad2 + acc[tm][3][r] * ad3;
#pragma unroll
            for (int m = 1; m < 16; m <<= 1) {
                p0 += __shfl_xor(p0, m); p1 += __shfl_xor(p1, m);
                q0 += __shfl_xor(q0, m); q1 += __shfl_xor(q1, m);
            }
            if (r16 == 0) {
                int row = row0 + tm * 16 + kseg * 4 + r;
                ssrc[row * NH + w * 2]     = p0;
                ssrc[row * NH + w * 2 + 1] = p1;
                sdst[row * NH + w * 2]     = q0;
                sdst[row * NH + w * 2 + 1] = q1;
            }
        }
    }

#pragma unroll
    for (int tm = 0; tm < 2; ++tm)
#pragma unroll
        for (int tn = 0; tn < 4; ++tn)
#pragma unroll
            for (int r = 0; r < 4; ++r)
                hs[(tm * 16 + kseg * 4 + r) * 264 + w * 64 + tn * 16 + r16] = (_Float16)acc[tm][tn][r];
    __syncthreads();
#pragma unroll
    for (int i = 0; i < 4; ++i) {
        int idx = i * 256 + tid;
        int rr = idx >> 5;
        int cc = idx & 31;
        f16x8 v = *(const f16x8*)&hs[rr * 264 + cc * 8];
        *(f16x8*)(Hh + (size_t)(row0 + rr) * 256 + cc * 8) = v;
    }
}

// ---------------- GEMM K=41 (fp32 VALU) + fused score dots, fp16 H out ----------------

__global__ __launch_bounds__(256) void gemm41(const float* __restrict__ X,
                                              const float* __restrict__ W,
                                              const float* __restrict__ a_src,
                                              const float* __restrict__ a_dst,
                                              _Float16* __restrict__ Hh,
                                              float* __restrict__ ssrc,
                                              float* __restrict__ sdst) {
    __shared__ float xs[32][44];
    int row0 = blockIdx.x * 32;
    int tid = threadIdx.x;
    int lane = tid & 63;
    int wave = tid >> 6;
    int c4 = lane * 4;
    int wrow = wave * 8;

    for (int idx = tid; idx < 32 * FIN; idx += 256) {
        int r = idx / FIN, k = idx - r * FIN;
        xs[r][k] = X[(size_t)(row0 + r) * FIN + k];
    }
    __syncthreads();

    float4 acc[8];
#pragma unroll
    for (int r = 0; r < 8; ++r) acc[r] = make_float4(0.f, 0.f, 0.f, 0.f);

    for (int k = 0; k < FIN; ++k) {
        float4 w0 = *reinterpret_cast<const float4*>(W + (size_t)k * HC + c4);
#pragma unroll
        for (int r = 0; r < 8; ++r) {
            float xv = xs[wrow + r][k];
            acc[r].x += xv * w0.x; acc[r].y += xv * w0.y; acc[r].z += xv * w0.z; acc[r].w += xv * w0.w;
        }
    }
    const float4 asv = *reinterpret_cast<const float4*>(a_src + c4);
    const float4 adv = *reinterpret_cast<const float4*>(a_dst + c4);
#pragma unroll
    for (int r = 0; r < 8; ++r) {
        int gr = row0 + wrow + r;
        f16x4 hv;
        hv[0] = (_Float16)acc[r].x; hv[1] = (_Float16)acc[r].y;
        hv[2] = (_Float16)acc[r].z; hv[3] = (_Float16)acc[r].w;
        *(f16x4*)(Hh + (size_t)gr * HC + c4) = hv;
        float ps = acc[r].x * asv.x + acc[r].y * asv.y + acc[r].z * asv.z + acc[r].w * asv.w;
        float pd = acc[r].x * adv.x + acc[r].y * adv.y + acc[r].z * adv.z + acc[r].w * adv.w;
        ps += __shfl_xor(ps, 1); pd += __shfl_xor(pd, 1);
        ps += __shfl_xor(ps, 2); pd += __shfl_xor(pd, 2);
        ps += __shfl_xor(ps, 4); pd += __shfl_xor(pd, 4);
        if ((lane & 7) == 0) {
            ssrc[gr * NH + (lane >> 3)] = ps;
            sdst[gr * NH + (lane >> 3)] = pd;
        }
    }
}

// ---------------- fused GAT aggregation + bias + BN(eval) + ELU ----------------
// Single pass (no max subtraction — softmax is shift-invariant and scores are
// O(1) here, so exp() in fp32 is safe). Lane owns 4 channels; head = lane>>3.
// 8x-batched: 8 broadcast colidx -> 8 score gathers -> 8 row gathers.

__global__ __launch_bounds__(256) void gat_agg(const int* __restrict__ row_ptr,
                                               const int* __restrict__ colidx,
                                               const float* __restrict__ ssrc,
                                               const float* __restrict__ sdst,
                                               const _Float16* __restrict__ h,
                                               const float* __restrict__ bias,
                                               const float* __restrict__ gamma,
                                               const float* __restrict__ beta,
                                               _Float16* __restrict__ outh) {
    int wave = (blockIdx.x * blockDim.x + threadIdx.x) >> 6;
    int lane = threadIdx.x & 63;
    if (wave >= N_NODES) return;
    int n = wave;
    int beg = row_ptr[n], end = row_ptr[n + 1];
    int deg = end - beg;

    int hd = lane >> 3;
    float sd = sdst[n * NH + hd];
    int c = lane * 4;
    float acc0 = 0.f, acc1 = 0.f, acc2 = 0.f, acc3 = 0.f, denom = 0.f;

    int i = 0;
    for (; i + 8 <= deg; i += 8) {
        int sidx[8];
#pragma unroll
        for (int j = 0; j < 8; ++j) sidx[j] = colidx[beg + i + j];
        float wv[8];
#pragma unroll
        for (int j = 0; j < 8; ++j) {
            float v = ssrc[sidx[j] * NH + hd] + sd;
            v = (v >= 0.f) ? v : 0.2f * v;
            wv[j] = __expf(v);
        }
        f16x4 hv[8];
#pragma unroll
        for (int j = 0; j < 8; ++j) hv[j] = *reinterpret_cast<const f16x4*>(h + (size_t)sidx[j] * HC + c);
#pragma unroll
        for (int j = 0; j < 8; ++j) {
            denom += wv[j];
            acc0 += wv[j] * (float)hv[j][0];
            acc1 += wv[j] * (float)hv[j][1];
            acc2 += wv[j] * (float)hv[j][2];
            acc3 += wv[j] * (float)hv[j][3];
        }
    }
    for (; i < deg; ++i) {
        int s = colidx[beg + i];
        float v = ssrc[s * NH + hd] + sd;
        v = (v >= 0.f) ? v : 0.2f * v;
        float wgt = __expf(v);
        denom += wgt;
        const f16x4 hv = *reinterpret_cast<const f16x4*>(h + (size_t)s * HC + c);
        acc0 += wgt * (float)hv[0]; acc1 += wgt * (float)hv[1];
        acc2 += wgt * (float)hv[2]; acc3 += wgt * (float)hv[3];
    }
    float inv = 1.0f / denom;
    const float bninv = 0.99999500003749981f;  // 1/sqrt(1+1e-5)
    float vals[4] = {acc0, acc1, acc2, acc3};
    f16x4 o;
#pragma unroll
    for (int j = 0; j < 4; ++j) {
        float v = vals[j] * inv + bias[c + j];
        v = v * (gamma[c + j] * bninv) + beta[c + j];
        v = (v > 0.f) ? v : (__expf(v) - 1.0f);
        o[j] = (_Float16)v;
    }
    *(f16x4*)(outh + (size_t)n * HC + c) = o;
}

// ---------------- pooling ----------------

__global__ __launch_bounds__(256) void pool_partial(const _Float16* __restrict__ h,
                                                    const int* __restrict__ gstart,
                                                    const int* __restrict__ gend,
                                                    float* __restrict__ psum,
                                                    float* __restrict__ pmax) {
    int g = blockIdx.x >> 4;
    int c = blockIdx.x & (PCHUNK - 1);
    int t = threadIdx.x;
    int s = gstart[g], e = gend[g];
    int len = e - s;
    int n0 = s + (int)(((long long)len * c) / PCHUNK);
    int n1 = s + (int)(((long long)len * (c + 1)) / PCHUNK);
    float sum = 0.f, mx = -3.0e38f;
    for (int n = n0; n < n1; ++n) {
        float v = (float)h[(size_t)n * HC + t];
        sum += v;
        mx = fmaxf(mx, v);
    }
    psum[(size_t)(g * PCHUNK + c) * HC + t] = sum;
    pmax[(size_t)(g * PCHUNK + c) * HC + t] = mx;
}

// ---------------- MLP head (fused pool-finalize + 3 FC layers) ----------------

__global__ __launch_bounds__(256) void mlp(const float* __restrict__ psum,
                                           const float* __restrict__ pmax,
                                           const int* __restrict__ gstart,
                                           const int* __restrict__ gend,
                                           const float* __restrict__ gsz,
                                           const float* __restrict__ fc1wT, const float* __restrict__ fc1b,
                                           const float* __restrict__ gf1, const float* __restrict__ bf1,
                                           const float* __restrict__ fc2w, const float* __restrict__ fc2b,
                                           const float* __restrict__ gf2, const float* __restrict__ bf2,
                                           const float* __restrict__ fc3w, const float* __restrict__ fc3b,
                                           float* __restrict__ out) {
    __shared__ __align__(16) float pr[514];
    __shared__ float z1[64];
    __shared__ float zz2[8][32];
    __shared__ float z2[32];
    int g = blockIdx.x;
    int t = threadIdx.x;
    const float bninv = 0.99999500003749981f;

    {
        float s = 0.f, m = -3.0e38f;
#pragma unroll
        for (int c = 0; c < PCHUNK; ++c) {
            s += psum[(size_t)(g * PCHUNK + c) * HC + t];
            m = fmaxf(m, pmax[(size_t)(g * PCHUNK + c) * HC + t]);
        }
        float cnt = (float)(gend[g] - gstart[g]);
        pr[t] = s / fmaxf(cnt, 1.f);
        pr[256 + t] = m;
        if (t < 2) pr[512 + t] = gsz[g * 2 + t];
    }
    __syncthreads();

    {
        int wv = t >> 6, lane = t & 63;
        float4 pa = *reinterpret_cast<const float4*>(&pr[lane * 8]);
        float4 pb = *reinterpret_cast<const float4*>(&pr[lane * 8 + 4]);
#pragma unroll 4
        for (int i = 0; i < 16; ++i) {
            int u = wv * 16 + i;
            const float* wrow = fc1wT + u * 520;
            float4 wa = *reinterpret_cast<const float4*>(wrow + lane * 8);
            float4 wb = *reinterpret_cast<const float4*>(wrow + lane * 8 + 4);
            float a = pa.x * wa.x + pa.y * wa.y + pa.z * wa.z + pa.w * wa.w
                    + pb.x * wb.x + pb.y * wb.y + pb.z * wb.z + pb.w * wb.w;
            if (lane == 0) a += pr[512] * wrow[512] + pr[513] * wrow[513];
            a += __shfl_xor(a, 1); a += __shfl_xor(a, 2); a += __shfl_xor(a, 4);
            a += __shfl_xor(a, 8); a += __shfl_xor(a, 16); a += __shfl_xor(a, 32);
            if (lane == 0) {
                a += fc1b[u];
                a = a * (gf1[u] * bninv) + bf1[u];
                z1[u] = fmaxf(a, 0.f);
            }
        }
    }
    __syncthreads();

    {
        int u = t & 31, sp = t >> 5;
        float b = 0.f;
#pragma unroll
        for (int k = sp * 8; k < sp * 8 + 8; ++k) b += z1[k] * fc2w[k * 32 + u];
        zz2[sp][u] = b;
    }
    __syncthreads();
    if (t < 32) {
        float b = 0.f;
#pragma unroll
        for (int sp = 0; sp < 8; ++sp) b += zz2[sp][t];
        b += fc2b[t];
        b = b * (gf2[t] * bninv) + bf2[t];
        z2[t] = fmaxf(b, 0.f);
    }
    __syncthreads();

    if (t < 2) {
        float c = 0.f;
#pragma unroll
        for (int k = 0; k < 32; ++k) c += z2[k] * fc3w[k * 2 + t];
        out[g * 2 + t] = c + fc3b[t];
    }
}

// ---------------- launch ----------------

extern "C" void kernel_launch(void* const* d_in, const int* in_sizes, int n_in,
                              void* d_out, int out_size, void* d_ws, size_t ws_size,
                              hipStream_t stream) {
    const float* x    = (const float*)d_in[0];
    const int*   ei   = (const int*)d_in[1];
    const int*   batch= (const int*)d_in[2];
    const float* gsz  = (const float*)d_in[3];
    const float* W1   = (const float*)d_in[4];
    const float* as1  = (const float*)d_in[5];
    const float* ad1  = (const float*)d_in[6];
    const float* b1   = (const float*)d_in[7];
    const float* g1   = (const float*)d_in[8];
    const float* be1  = (const float*)d_in[9];
    const float* W2   = (const float*)d_in[10];
    const float* as2  = (const float*)d_in[11];
    const float* ad2  = (const float*)d_in[12];
    const float* b2   = (const float*)d_in[13];
    const float* g2   = (const float*)d_in[14];
    const float* be2  = (const float*)d_in[15];
    const float* fc1w = (const float*)d_in[16];
    const float* fc1b = (const float*)d_in[17];
    const float* gf1  = (const float*)d_in[18];
    const float* bf1  = (const float*)d_in[19];
    const float* fc2w = (const float*)d_in[20];
    const float* fc2b = (const float*)d_in[21];
    const float* gf2  = (const float*)d_in[22];
    const float* bf2  = (const float*)d_in[23];
    const float* fc3w = (const float*)d_in[24];
    const float* fc3b = (const float*)d_in[25];
    float* out = (float*)d_out;

    char* w = (char*)d_ws;
    _Float16* h_half   = (_Float16*)w; w += (size_t)N_NODES * HC * 2;   // 10.24 MB
    _Float16* act_half = (_Float16*)w; w += (size_t)N_NODES * HC * 2;   // 10.24 MB
    _Float16* act2_half= (_Float16*)w; w += (size_t)N_NODES * HC * 2;   // 10.24 MB
    _Float16* Wt       = (_Float16*)w; w += (size_t)HC * HC * 2;        // 128 KB
    float* fc1wT       = (float*)w;    w += (size_t)64 * 520 * 4;       // 133 KB
    float* ssrc        = (float*)w;    w += (size_t)N_NODES * NH * 4;
    float* sdst        = (float*)w;    w += (size_t)N_NODES * NH * 4;
    int* row_ptr  = (int*)w;   w += (size_t)(N_NODES + 1) * 4;
    int* cursor   = (int*)w;   w += (size_t)N_NODES * 4;
    // cnt, gstart, gend contiguous -> single memset
    int* cnt      = (int*)w;   w += (size_t)N_NODES * 4;
    int* gstart   = (int*)w;   w += 64 * 4;
    int* gend     = (int*)w;   w += 64 * 4;
    int* colidx   = (int*)w;   w += (size_t)(E_EDGES + N_NODES) * 4;
    int* partial  = (int*)w;   w += 64 * 4;

    // pool partials alias h_half (dead after gat_agg#2)
    float* psum = (float*)h_half;
    float* pmax = psum + (size_t)NG * PCHUNK * HC;

    hipMemsetAsync(cnt, 0, (size_t)(N_NODES + 128) * 4, stream);  // cnt + gstart + gend

    prep<<<224, 256, 0, stream>>>(W2, Wt, fc1w, fc1wT, batch, gstart, gend);
    hist<<<1250, 256, 0, stream>>>(ei, cnt);
    scanA<<<40, 512, 0, stream>>>(cnt, partial);
    scanB<<<1, 64, 0, stream>>>(partial);
    scanC<<<40, 512, 0, stream>>>(cnt, partial, row_ptr, cursor, colidx);
    fill_csr<<<1250, 256, 0, stream>>>(ei, cursor, colidx);

    gemm41<<<625, 256, 0, stream>>>(x, W1, as1, ad1, h_half, ssrc, sdst);
    gat_agg<<<5000, 256, 0, stream>>>(row_ptr, colidx, ssrc, sdst, h_half, b1, g1, be1, act_half);

    gemm256h<<<625, 256, 0, stream>>>(act_half, Wt, as2, ad2, h_half, ssrc, sdst);
    gat_agg<<<5000, 256, 0, stream>>>(row_ptr, colidx, ssrc, sdst, h_half, b2, g2, be2, act2_half);

    pool_partial<<<NG * PCHUNK, 256, 0, stream>>>(act2_half, gstart, gend, psum, pmax);
    mlp<<<NG, 256, 0, stream>>>(psum, pmax, gstart, gend, gsz,
                                fc1wT, fc1b, gf1, bf1, fc2w, fc2b, gf2, bf2, fc3w, fc3b, out);
}

// Round 12
// 171.232 us; speedup vs baseline: 1.3599x; 1.0482x over previous
//
#include <hip/hip_runtime.h>
#include <hip/hip_bf16.h>

#define N_NODES 20000
#define E_EDGES 320000
#define NH 8
#define NC 32
#define HC 256
#define FIN 41
#define NG 64
#define PCHUNK 16

typedef _Float16 f16x4 __attribute__((ext_vector_type(4)));
typedef _Float16 f16x8 __attribute__((ext_vector_type(8)));
typedef float f32x4v __attribute__((ext_vector_type(4)));

// ---------------- CSR build ----------------
// cnt[] holds EDGE counts only (zeroed by memset); row size = cnt[n] + 1 (self loop).

__global__ __launch_bounds__(256) void hist(const int* __restrict__ ei, int* cnt) {
    int e = blockIdx.x * 256 + threadIdx.x;
    if (e < E_EDGES) atomicAdd(&cnt[ei[E_EDGES + e]], 1);
}

__global__ __launch_bounds__(512) void scanA(const int* __restrict__ cnt, int* partial) {
    __shared__ int red[512];
    int n = blockIdx.x * 512 + threadIdx.x;
    int v = (n < N_NODES) ? cnt[n] + 1 : 0;
    red[threadIdx.x] = v; __syncthreads();
    for (int off = 256; off > 0; off >>= 1) {
        if (threadIdx.x < off) red[threadIdx.x] += red[threadIdx.x + off];
        __syncthreads();
    }
    if (threadIdx.x == 0) partial[blockIdx.x] = red[0];
}

__global__ __launch_bounds__(64) void scanB(int* partial) {
    int t = threadIdx.x;
    int v = (t < 40) ? partial[t] : 0;
    int orig = v;
    for (int off = 1; off < 64; off <<= 1) {
        int y = __shfl_up(v, off);
        if (t >= off) v += y;
    }
    if (t < 40) partial[t] = v - orig;  // exclusive
}

__global__ __launch_bounds__(512) void scanC(const int* __restrict__ cnt, const int* __restrict__ partial,
                                             int* row_ptr, int* cursor, int* colidx) {
    __shared__ int buf[512];
    int t = threadIdx.x;
    int n = blockIdx.x * 512 + t;
    int v = (n < N_NODES) ? cnt[n] + 1 : 0;
    int x = v;
    buf[t] = x; __syncthreads();
    for (int off = 1; off < 512; off <<= 1) {
        int y = (t >= off) ? buf[t - off] : 0;
        __syncthreads();
        x += y; buf[t] = x; __syncthreads();
    }
    int excl = partial[blockIdx.x] + x - v;
    if (n < N_NODES) {
        row_ptr[n] = excl;
        cursor[n] = excl + 1;     // self loop occupies slot 0
        colidx[excl] = n;         // self loop
    }
    if (n == 0) row_ptr[N_NODES] = E_EDGES + N_NODES;
}

__global__ __launch_bounds__(256) void fill_csr(const int* __restrict__ ei, int* cursor, int* colidx) {
    int e = blockIdx.x * 256 + threadIdx.x;
    if (e >= E_EDGES) return;
    int d = ei[E_EDGES + e];
    int s = ei[e];
    int pos = atomicAdd(&cursor[d], 1);
    colidx[pos] = s;
}

// ---------------- prep: wconv (blocks 0..15) + fc1conv (16..144) + graph_ranges (145..223) ----------------

__global__ __launch_bounds__(256) void prep(const float* __restrict__ W, _Float16* __restrict__ Wt,
                                            const float* __restrict__ fc1w, float* __restrict__ fc1wT,
                                            const int* __restrict__ batch, int* gstart, int* gend) {
    __shared__ float tile[64][65];
    int b = blockIdx.x;
    int t = threadIdx.x;
    if (b < 16) {
        int tr = (b >> 2) * 64;
        int tc = (b & 3) * 64;
        int rr = t >> 6, cc = t & 63;
#pragma unroll
        for (int j = 0; j < 16; ++j) {
            int row = j * 4 + rr;
            tile[row][cc] = W[(size_t)(tr + row) * 256 + tc + cc];
        }
        __syncthreads();
#pragma unroll
        for (int j = 0; j < 16; ++j) {
            int row = j * 4 + rr;
            Wt[(size_t)(tc + row) * 256 + tr + cc] = (_Float16)tile[cc][row];
        }
    } else if (b < 145) {
        int id = (b - 16) * 256 + t;
        if (id < 64 * 514) {
            int u = id / 514, kk = id - u * 514;
            fc1wT[u * 520 + kk] = fc1w[kk * 64 + u];
        }
    } else {
        int n = (b - 145) * 256 + t;
        if (n < N_NODES) {
            int bb = batch[n];
            if (n == 0) gstart[bb] = 0;
            else {
                int pb = batch[n - 1];
                if (pb != bb) { gstart[bb] = n; gend[pb] = n; }
            }
            if (n == N_NODES - 1) gend[bb] = N_NODES;
        }
    }
}

// ---------------- GEMM K=256 via MFMA fp16 (16x16x32), B-resident-in-LDS ----------------
// block = 64 rows x 32 cols (head = blockIdx.x & 7); grid = 313*8 = 2504.
// B tile (32x256 fp16, 16KB) staged to LDS once (coalesced), each wave holds its
// 16 B-frags + 8 A-frags in registers, 16 MFMAs back-to-back. Fused score dots.

__global__ __launch_bounds__(256) void gemm256h(const _Float16* __restrict__ Xh,
                                                const _Float16* __restrict__ Wt,
                                                const float* __restrict__ a_src,
                                                const float* __restrict__ a_dst,
                                                _Float16* __restrict__ Hh,
                                                float* __restrict__ ssrc,
                                                float* __restrict__ sdst) {
    __shared__ _Float16 bs[32 * 272];   // B: 32 cols x 256 K, padded stride 272
    __shared__ _Float16 hs[64 * 40];    // out transpose buffer
    int row0 = (blockIdx.x >> 3) * 64;
    int wcol = blockIdx.x & 7;          // head
    int c0 = wcol * 32;
    int tid = threadIdx.x;
    int lane = tid & 63;
    int v = tid >> 6;                   // wave: rows row0 + v*16 ..
    int r16 = lane & 15;
    int kseg = lane >> 4;

    // stage B (fully coalesced: 32 threads per 512B row)
#pragma unroll
    for (int i = 0; i < 4; ++i) {
        int chunk = i * 256 + tid;      // 1024 chunks of 8 halfs
        int c = chunk >> 5;
        int k = (chunk & 31) * 8;
        f16x8 x = *(const f16x8*)(Wt + (size_t)(c0 + c) * 256 + k);
        *(f16x8*)(&bs[c * 272 + k]) = x;
    }

    // A-frags: all 8 K-steps up-front (independent 16B loads)
    int arow = row0 + v * 16 + r16;
    const _Float16* XA = Xh + (size_t)arow * 256 + kseg * 8;
    f16x8 af[8];
#pragma unroll
    for (int s = 0; s < 8; ++s) af[s] = *(const f16x8*)(XA + s * 32);

    __syncthreads();

    // B-frags from LDS (stride 272: bank = (8*r16+4*kseg)%32 -> 2-way, free)
    f16x8 bf[2][8];
#pragma unroll
    for (int tn = 0; tn < 2; ++tn)
#pragma unroll
        for (int s = 0; s < 8; ++s)
            bf[tn][s] = *(const f16x8*)(&bs[(tn * 16 + r16) * 272 + kseg * 8 + s * 32]);

    f32x4v acc[2];
    acc[0] = (f32x4v){0.f, 0.f, 0.f, 0.f};
    acc[1] = (f32x4v){0.f, 0.f, 0.f, 0.f};
#pragma unroll
    for (int s = 0; s < 8; ++s) {
        acc[0] = __builtin_amdgcn_mfma_f32_16x16x32_f16(af[s], bf[0][s], acc[0], 0, 0, 0);
        acc[1] = __builtin_amdgcn_mfma_f32_16x16x32_f16(af[s], bf[1][s], acc[1], 0, 0, 0);
    }

    // fused score dots for head wcol (reduce over the 32 cols = lane&15 x 2 tiles)
    float as0 = a_src[c0 + r16], as1 = a_src[c0 + 16 + r16];
    float ad0 = a_dst[c0 + r16], ad1 = a_dst[c0 + 16 + r16];
#pragma unroll
    for (int r = 0; r < 4; ++r) {
        float p = acc[0][r] * as0 + acc[1][r] * as1;
        float q = acc[0][r] * ad0 + acc[1][r] * ad1;
        p += __shfl_xor(p, 1); q += __shfl_xor(q, 1);
        p += __shfl_xor(p, 2); q += __shfl_xor(q, 2);
        p += __shfl_xor(p, 4); q += __shfl_xor(q, 4);
        p += __shfl_xor(p, 8); q += __shfl_xor(q, 8);
        int row = row0 + v * 16 + kseg * 4 + r;
        if (r16 == 0 && row < N_NODES) {
            ssrc[row * NH + wcol] = p;
            sdst[row * NH + wcol] = q;
        }
    }

    // H (fp16) via LDS transpose
#pragma unroll
    for (int tn = 0; tn < 2; ++tn)
#pragma unroll
        for (int r = 0; r < 4; ++r)
            hs[(v * 16 + kseg * 4 + r) * 40 + tn * 16 + r16] = (_Float16)acc[tn][r];
    __syncthreads();
    {
        int row = tid >> 2;
        int c8 = (tid & 3) * 8;
        if (row0 + row < N_NODES) {
            f16x8 x = *(const f16x8*)&hs[row * 40 + c8];
            *(f16x8*)(Hh + (size_t)(row0 + row) * 256 + c0 + c8) = x;
        }
    }
}

// ---------------- GEMM K=41 (fp32 VALU) + fused score dots, fp16 H out ----------------

__global__ __launch_bounds__(256) void gemm41(const float* __restrict__ X,
                                              const float* __restrict__ W,
                                              const float* __restrict__ a_src,
                                              const float* __restrict__ a_dst,
                                              _Float16* __restrict__ Hh,
                                              float* __restrict__ ssrc,
                                              float* __restrict__ sdst) {
    __shared__ float xs[32][44];
    int row0 = blockIdx.x * 32;
    int tid = threadIdx.x;
    int lane = tid & 63;
    int wave = tid >> 6;
    int c4 = lane * 4;
    int wrow = wave * 8;

    for (int idx = tid; idx < 32 * FIN; idx += 256) {
        int r = idx / FIN, k = idx - r * FIN;
        xs[r][k] = X[(size_t)(row0 + r) * FIN + k];
    }
    __syncthreads();

    float4 acc[8];
#pragma unroll
    for (int r = 0; r < 8; ++r) acc[r] = make_float4(0.f, 0.f, 0.f, 0.f);

    for (int k = 0; k < FIN; ++k) {
        float4 w0 = *reinterpret_cast<const float4*>(W + (size_t)k * HC + c4);
#pragma unroll
        for (int r = 0; r < 8; ++r) {
            float xv = xs[wrow + r][k];
            acc[r].x += xv * w0.x; acc[r].y += xv * w0.y; acc[r].z += xv * w0.z; acc[r].w += xv * w0.w;
        }
    }
    const float4 asv = *reinterpret_cast<const float4*>(a_src + c4);
    const float4 adv = *reinterpret_cast<const float4*>(a_dst + c4);
#pragma unroll
    for (int r = 0; r < 8; ++r) {
        int gr = row0 + wrow + r;
        f16x4 hv;
        hv[0] = (_Float16)acc[r].x; hv[1] = (_Float16)acc[r].y;
        hv[2] = (_Float16)acc[r].z; hv[3] = (_Float16)acc[r].w;
        *(f16x4*)(Hh + (size_t)gr * HC + c4) = hv;
        float ps = acc[r].x * asv.x + acc[r].y * asv.y + acc[r].z * asv.z + acc[r].w * asv.w;
        float pd = acc[r].x * adv.x + acc[r].y * adv.y + acc[r].z * adv.z + acc[r].w * adv.w;
        ps += __shfl_xor(ps, 1); pd += __shfl_xor(pd, 1);
        ps += __shfl_xor(ps, 2); pd += __shfl_xor(pd, 2);
        ps += __shfl_xor(ps, 4); pd += __shfl_xor(pd, 4);
        if ((lane & 7) == 0) {
            ssrc[gr * NH + (lane >> 3)] = ps;
            sdst[gr * NH + (lane >> 3)] = pd;
        }
    }
}

// ---------------- fused GAT aggregation + bias + BN(eval) + ELU ----------------
// Single pass (softmax shift-invariance; scores O(1) -> exp safe in fp32).

__global__ __launch_bounds__(256) void gat_agg(const int* __restrict__ row_ptr,
                                               const int* __restrict__ colidx,
                                               const float* __restrict__ ssrc,
                                               const float* __restrict__ sdst,
                                               const _Float16* __restrict__ h,
                                               const float* __restrict__ bias,
                                               const float* __restrict__ gamma,
                                               const float* __restrict__ beta,
                                               _Float16* __restrict__ outh) {
    int wave = (blockIdx.x * blockDim.x + threadIdx.x) >> 6;
    int lane = threadIdx.x & 63;
    if (wave >= N_NODES) return;
    int n = wave;
    int beg = row_ptr[n], end = row_ptr[n + 1];
    int deg = end - beg;

    int hd = lane >> 3;
    float sd = sdst[n * NH + hd];
    int c = lane * 4;
    float acc0 = 0.f, acc1 = 0.f, acc2 = 0.f, acc3 = 0.f, denom = 0.f;

    int i = 0;
    for (; i + 8 <= deg; i += 8) {
        int sidx[8];
#pragma unroll
        for (int j = 0; j < 8; ++j) sidx[j] = colidx[beg + i + j];
        float wv[8];
#pragma unroll
        for (int j = 0; j < 8; ++j) {
            float v = ssrc[sidx[j] * NH + hd] + sd;
            v = (v >= 0.f) ? v : 0.2f * v;
            wv[j] = __expf(v);
        }
        f16x4 hv[8];
#pragma unroll
        for (int j = 0; j < 8; ++j) hv[j] = *reinterpret_cast<const f16x4*>(h + (size_t)sidx[j] * HC + c);
#pragma unroll
        for (int j = 0; j < 8; ++j) {
            denom += wv[j];
            acc0 += wv[j] * (float)hv[j][0];
            acc1 += wv[j] * (float)hv[j][1];
            acc2 += wv[j] * (float)hv[j][2];
            acc3 += wv[j] * (float)hv[j][3];
        }
    }
    for (; i < deg; ++i) {
        int s = colidx[beg + i];
        float v = ssrc[s * NH + hd] + sd;
        v = (v >= 0.f) ? v : 0.2f * v;
        float wgt = __expf(v);
        denom += wgt;
        const f16x4 hv = *reinterpret_cast<const f16x4*>(h + (size_t)s * HC + c);
        acc0 += wgt * (float)hv[0]; acc1 += wgt * (float)hv[1];
        acc2 += wgt * (float)hv[2]; acc3 += wgt * (float)hv[3];
    }
    float inv = 1.0f / denom;
    const float bninv = 0.99999500003749981f;  // 1/sqrt(1+1e-5)
    float vals[4] = {acc0, acc1, acc2, acc3};
    f16x4 o;
#pragma unroll
    for (int j = 0; j < 4; ++j) {
        float v = vals[j] * inv + bias[c + j];
        v = v * (gamma[c + j] * bninv) + beta[c + j];
        v = (v > 0.f) ? v : (__expf(v) - 1.0f);
        o[j] = (_Float16)v;
    }
    *(f16x4*)(outh + (size_t)n * HC + c) = o;
}

// ---------------- pooling ----------------

__global__ __launch_bounds__(256) void pool_partial(const _Float16* __restrict__ h,
                                                    const int* __restrict__ gstart,
                                                    const int* __restrict__ gend,
                                                    float* __restrict__ psum,
                                                    float* __restrict__ pmax) {
    int g = blockIdx.x >> 4;
    int c = blockIdx.x & (PCHUNK - 1);
    int t = threadIdx.x;
    int s = gstart[g], e = gend[g];
    int len = e - s;
    int n0 = s + (int)(((long long)len * c) / PCHUNK);
    int n1 = s + (int)(((long long)len * (c + 1)) / PCHUNK);
    float sum = 0.f, mx = -3.0e38f;
    for (int n = n0; n < n1; ++n) {
        float v = (float)h[(size_t)n * HC + t];
        sum += v;
        mx = fmaxf(mx, v);
    }
    psum[(size_t)(g * PCHUNK + c) * HC + t] = sum;
    pmax[(size_t)(g * PCHUNK + c) * HC + t] = mx;
}

// ---------------- MLP head (fused pool-finalize + 3 FC layers) ----------------

__global__ __launch_bounds__(256) void mlp(const float* __restrict__ psum,
                                           const float* __restrict__ pmax,
                                           const int* __restrict__ gstart,
                                           const int* __restrict__ gend,
                                           const float* __restrict__ gsz,
                                           const float* __restrict__ fc1wT, const float* __restrict__ fc1b,
                                           const float* __restrict__ gf1, const float* __restrict__ bf1,
                                           const float* __restrict__ fc2w, const float* __restrict__ fc2b,
                                           const float* __restrict__ gf2, const float* __restrict__ bf2,
                                           const float* __restrict__ fc3w, const float* __restrict__ fc3b,
                                           float* __restrict__ out) {
    __shared__ __align__(16) float pr[514];
    __shared__ float z1[64];
    __shared__ float zz2[8][32];
    __shared__ float z2[32];
    int g = blockIdx.x;
    int t = threadIdx.x;
    const float bninv = 0.99999500003749981f;

    {
        float s = 0.f, m = -3.0e38f;
#pragma unroll
        for (int c = 0; c < PCHUNK; ++c) {
            s += psum[(size_t)(g * PCHUNK + c) * HC + t];
            m = fmaxf(m, pmax[(size_t)(g * PCHUNK + c) * HC + t]);
        }
        float cnt = (float)(gend[g] - gstart[g]);
        pr[t] = s / fmaxf(cnt, 1.f);
        pr[256 + t] = m;
        if (t < 2) pr[512 + t] = gsz[g * 2 + t];
    }
    __syncthreads();

    {
        int wv = t >> 6, lane = t & 63;
        float4 pa = *reinterpret_cast<const float4*>(&pr[lane * 8]);
        float4 pb = *reinterpret_cast<const float4*>(&pr[lane * 8 + 4]);
#pragma unroll 4
        for (int i = 0; i < 16; ++i) {
            int u = wv * 16 + i;
            const float* wrow = fc1wT + u * 520;
            float4 wa = *reinterpret_cast<const float4*>(wrow + lane * 8);
            float4 wb = *reinterpret_cast<const float4*>(wrow + lane * 8 + 4);
            float a = pa.x * wa.x + pa.y * wa.y + pa.z * wa.z + pa.w * wa.w
                    + pb.x * wb.x + pb.y * wb.y + pb.z * wb.z + pb.w * wb.w;
            if (lane == 0) a += pr[512] * wrow[512] + pr[513] * wrow[513];
            a += __shfl_xor(a, 1); a += __shfl_xor(a, 2); a += __shfl_xor(a, 4);
            a += __shfl_xor(a, 8); a += __shfl_xor(a, 16); a += __shfl_xor(a, 32);
            if (lane == 0) {
                a += fc1b[u];
                a = a * (gf1[u] * bninv) + bf1[u];
                z1[u] = fmaxf(a, 0.f);
            }
        }
    }
    __syncthreads();

    {
        int u = t & 31, sp = t >> 5;
        float b = 0.f;
#pragma unroll
        for (int k = sp * 8; k < sp * 8 + 8; ++k) b += z1[k] * fc2w[k * 32 + u];
        zz2[sp][u] = b;
    }
    __syncthreads();
    if (t < 32) {
        float b = 0.f;
#pragma unroll
        for (int sp = 0; sp < 8; ++sp) b += zz2[sp][t];
        b += fc2b[t];
        b = b * (gf2[t] * bninv) + bf2[t];
        z2[t] = fmaxf(b, 0.f);
    }
    __syncthreads();

    if (t < 2) {
        float c = 0.f;
#pragma unroll
        for (int k = 0; k < 32; ++k) c += z2[k] * fc3w[k * 2 + t];
        out[g * 2 + t] = c + fc3b[t];
    }
}

// ---------------- launch ----------------

extern "C" void kernel_launch(void* const* d_in, const int* in_sizes, int n_in,
                              void* d_out, int out_size, void* d_ws, size_t ws_size,
                              hipStream_t stream) {
    const float* x    = (const float*)d_in[0];
    const int*   ei   = (const int*)d_in[1];
    const int*   batch= (const int*)d_in[2];
    const float* gsz  = (const float*)d_in[3];
    const float* W1   = (const float*)d_in[4];
    const float* as1  = (const float*)d_in[5];
    const float* ad1  = (const float*)d_in[6];
    const float* b1   = (const float*)d_in[7];
    const float* g1   = (const float*)d_in[8];
    const float* be1  = (const float*)d_in[9];
    const float* W2   = (const float*)d_in[10];
    const float* as2  = (const float*)d_in[11];
    const float* ad2  = (const float*)d_in[12];
    const float* b2   = (const float*)d_in[13];
    const float* g2   = (const float*)d_in[14];
    const float* be2  = (const float*)d_in[15];
    const float* fc1w = (const float*)d_in[16];
    const float* fc1b = (const float*)d_in[17];
    const float* gf1  = (const float*)d_in[18];
    const float* bf1  = (const float*)d_in[19];
    const float* fc2w = (const float*)d_in[20];
    const float* fc2b = (const float*)d_in[21];
    const float* gf2  = (const float*)d_in[22];
    const float* bf2  = (const float*)d_in[23];
    const float* fc3w = (const float*)d_in[24];
    const float* fc3b = (const float*)d_in[25];
    float* out = (float*)d_out;

    char* w = (char*)d_ws;
    _Float16* h_half   = (_Float16*)w; w += (size_t)N_NODES * HC * 2;   // 10.24 MB
    _Float16* act_half = (_Float16*)w; w += (size_t)N_NODES * HC * 2;   // 10.24 MB
    _Float16* act2_half= (_Float16*)w; w += (size_t)N_NODES * HC * 2;   // 10.24 MB
    _Float16* Wt       = (_Float16*)w; w += (size_t)HC * HC * 2;        // 128 KB
    float* fc1wT       = (float*)w;    w += (size_t)64 * 520 * 4;       // 133 KB
    float* ssrc        = (float*)w;    w += (size_t)N_NODES * NH * 4;
    float* sdst        = (float*)w;    w += (size_t)N_NODES * NH * 4;
    int* row_ptr  = (int*)w;   w += (size_t)(N_NODES + 1) * 4;
    int* cursor   = (int*)w;   w += (size_t)N_NODES * 4;
    // cnt, gstart, gend contiguous -> single memset
    int* cnt      = (int*)w;   w += (size_t)N_NODES * 4;
    int* gstart   = (int*)w;   w += 64 * 4;
    int* gend     = (int*)w;   w += 64 * 4;
    int* colidx   = (int*)w;   w += (size_t)(E_EDGES + N_NODES) * 4;
    int* partial  = (int*)w;   w += 64 * 4;

    // pool partials alias h_half (dead after gat_agg#2)
    float* psum = (float*)h_half;
    float* pmax = psum + (size_t)NG * PCHUNK * HC;

    hipMemsetAsync(cnt, 0, (size_t)(N_NODES + 128) * 4, stream);  // cnt + gstart + gend

    prep<<<224, 256, 0, stream>>>(W2, Wt, fc1w, fc1wT, batch, gstart, gend);
    hist<<<1250, 256, 0, stream>>>(ei, cnt);
    scanA<<<40, 512, 0, stream>>>(cnt, partial);
    scanB<<<1, 64, 0, stream>>>(partial);
    scanC<<<40, 512, 0, stream>>>(cnt, partial, row_ptr, cursor, colidx);
    fill_csr<<<1250, 256, 0, stream>>>(ei, cursor, colidx);

    gemm41<<<625, 256, 0, stream>>>(x, W1, as1, ad1, h_half, ssrc, sdst);
    gat_agg<<<5000, 256, 0, stream>>>(row_ptr, colidx, ssrc, sdst, h_half, b1, g1, be1, act_half);

    gemm256h<<<2504, 256, 0, stream>>>(act_half, Wt, as2, ad2, h_half, ssrc, sdst);
    gat_agg<<<5000, 256, 0, stream>>>(row_ptr, colidx, ssrc, sdst, h_half, b2, g2, be2, act2_half);

    pool_partial<<<NG * PCHUNK, 256, 0, stream>>>(act2_half, gstart, gend, psum, pmax);
    mlp<<<NG, 256, 0, stream>>>(psum, pmax, gstart, gend, gsz,
                                fc1wT, fc1b, gf1, bf1, fc2w, fc2b, gf2, bf2, fc3w, fc3b, out);
}

// Round 13
// 165.887 us; speedup vs baseline: 1.4037x; 1.0322x over previous
//
#include <hip/hip_runtime.h>
#include <hip/hip_bf16.h>

#define N_NODES 20000
#define E_EDGES 320000
#define NH 8
#define NC 32
#define HC 256
#define FIN 41
#define NG 64
#define PCHUNK 16
#define NPAD 20032

typedef _Float16 f16x4 __attribute__((ext_vector_type(4)));
typedef _Float16 f16x8 __attribute__((ext_vector_type(8)));
typedef float f32x4v __attribute__((ext_vector_type(4)));

// ---------------- CSR build ----------------
// cnt[] holds EDGE counts only (zeroed by memset); row size = cnt[n] + 1 (self loop).

__global__ __launch_bounds__(256) void hist(const int* __restrict__ ei, int* cnt) {
    int e = blockIdx.x * 256 + threadIdx.x;
    if (e < E_EDGES) atomicAdd(&cnt[ei[E_EDGES + e]], 1);
}

__global__ __launch_bounds__(512) void scanA(const int* __restrict__ cnt, int* partial) {
    __shared__ int red[512];
    int n = blockIdx.x * 512 + threadIdx.x;
    int v = (n < N_NODES) ? cnt[n] + 1 : 0;
    red[threadIdx.x] = v; __syncthreads();
    for (int off = 256; off > 0; off >>= 1) {
        if (threadIdx.x < off) red[threadIdx.x] += red[threadIdx.x + off];
        __syncthreads();
    }
    if (threadIdx.x == 0) partial[blockIdx.x] = red[0];
}

__global__ __launch_bounds__(64) void scanB(int* partial) {
    int t = threadIdx.x;
    int v = (t < 40) ? partial[t] : 0;
    int orig = v;
    for (int off = 1; off < 64; off <<= 1) {
        int y = __shfl_up(v, off);
        if (t >= off) v += y;
    }
    if (t < 40) partial[t] = v - orig;  // exclusive
}

__global__ __launch_bounds__(512) void scanC(const int* __restrict__ cnt, const int* __restrict__ partial,
                                             int* row_ptr, int* cursor, int* colidx) {
    __shared__ int buf[512];
    int t = threadIdx.x;
    int n = blockIdx.x * 512 + t;
    int v = (n < N_NODES) ? cnt[n] + 1 : 0;
    int x = v;
    buf[t] = x; __syncthreads();
    for (int off = 1; off < 512; off <<= 1) {
        int y = (t >= off) ? buf[t - off] : 0;
        __syncthreads();
        x += y; buf[t] = x; __syncthreads();
    }
    int excl = partial[blockIdx.x] + x - v;
    if (n < N_NODES) {
        row_ptr[n] = excl;
        cursor[n] = excl + 1;     // self loop occupies slot 0
        colidx[excl] = n;         // self loop
    }
    if (n == 0) row_ptr[N_NODES] = E_EDGES + N_NODES;
}

__global__ __launch_bounds__(256) void fill_csr(const int* __restrict__ ei, int* cursor, int* colidx) {
    int e = blockIdx.x * 256 + threadIdx.x;
    if (e >= E_EDGES) return;
    int d = ei[E_EDGES + e];
    int s = ei[e];
    int pos = atomicAdd(&cursor[d], 1);
    colidx[pos] = s;
}

// ---------------- prep ----------------
// blocks 0..15:    W2 -> fp16 col-major Wt[256][256]
// blocks 16..144:  fc1w -> fc1wT[64][520]
// blocks 145..223: graph_ranges
// blocks 224..287: W1 [41][256] -> fp16 col-major W1t[256][64] (zero-padded K)
// blocks 288..913: x [20000][41] -> fp16 xpad[20032][64] (zero-padded)

__global__ __launch_bounds__(256) void prep(const float* __restrict__ W, _Float16* __restrict__ Wt,
                                            const float* __restrict__ fc1w, float* __restrict__ fc1wT,
                                            const int* __restrict__ batch, int* gstart, int* gend,
                                            const float* __restrict__ W1, _Float16* __restrict__ W1t,
                                            const float* __restrict__ x, _Float16* __restrict__ xpad) {
    __shared__ float tile[64][65];
    int b = blockIdx.x;
    int t = threadIdx.x;
    if (b < 16) {
        int tr = (b >> 2) * 64;
        int tc = (b & 3) * 64;
        int rr = t >> 6, cc = t & 63;
#pragma unroll
        for (int j = 0; j < 16; ++j) {
            int row = j * 4 + rr;
            tile[row][cc] = W[(size_t)(tr + row) * 256 + tc + cc];
        }
        __syncthreads();
#pragma unroll
        for (int j = 0; j < 16; ++j) {
            int row = j * 4 + rr;
            Wt[(size_t)(tc + row) * 256 + tr + cc] = (_Float16)tile[cc][row];
        }
    } else if (b < 145) {
        int id = (b - 16) * 256 + t;
        if (id < 64 * 514) {
            int u = id / 514, kk = id - u * 514;
            fc1wT[u * 520 + kk] = fc1w[kk * 64 + u];
        }
    } else if (b < 224) {
        int n = (b - 145) * 256 + t;
        if (n < N_NODES) {
            int bb = batch[n];
            if (n == 0) gstart[bb] = 0;
            else {
                int pb = batch[n - 1];
                if (pb != bb) { gstart[bb] = n; gend[pb] = n; }
            }
            if (n == N_NODES - 1) gend[bb] = N_NODES;
        }
    } else if (b < 288) {
        int id = (b - 224) * 256 + t;       // 16384 = 256 cols x 64 K
        int n = id >> 6, k = id & 63;
        W1t[id] = (k < FIN) ? (_Float16)W1[k * 256 + n] : (_Float16)0.f;
    } else {
        int row = (b - 288) * 32 + (t >> 3);
        int c8 = (t & 7) * 8;
        f16x8 v;
#pragma unroll
        for (int j = 0; j < 8; ++j) {
            int c = c8 + j;
            float f = (row < N_NODES && c < FIN) ? x[(size_t)row * FIN + c] : 0.f;
            v[j] = (_Float16)f;
        }
        if (row < NPAD) *(f16x8*)(xpad + (size_t)row * 64 + c8) = v;
    }
}

// ---------------- GEMM K=256 via MFMA fp16 (16x16x32), B-resident-in-LDS ----------------
// block = 64 rows x 32 cols (head = blockIdx.x & 7); grid = 313*8 = 2504.

__global__ __launch_bounds__(256) void gemm256h(const _Float16* __restrict__ Xh,
                                                const _Float16* __restrict__ Wt,
                                                const float* __restrict__ a_src,
                                                const float* __restrict__ a_dst,
                                                _Float16* __restrict__ Hh,
                                                float* __restrict__ ssrc,
                                                float* __restrict__ sdst) {
    __shared__ _Float16 bs[32 * 272];   // B: 32 cols x 256 K, padded stride 272
    __shared__ _Float16 hs[64 * 40];    // out transpose buffer
    int row0 = (blockIdx.x >> 3) * 64;
    int wcol = blockIdx.x & 7;          // head
    int c0 = wcol * 32;
    int tid = threadIdx.x;
    int lane = tid & 63;
    int v = tid >> 6;
    int r16 = lane & 15;
    int kseg = lane >> 4;

#pragma unroll
    for (int i = 0; i < 4; ++i) {
        int chunk = i * 256 + tid;
        int c = chunk >> 5;
        int k = (chunk & 31) * 8;
        f16x8 xv = *(const f16x8*)(Wt + (size_t)(c0 + c) * 256 + k);
        *(f16x8*)(&bs[c * 272 + k]) = xv;
    }

    int arow = row0 + v * 16 + r16;
    const _Float16* XA = Xh + (size_t)arow * 256 + kseg * 8;
    f16x8 af[8];
#pragma unroll
    for (int s = 0; s < 8; ++s) af[s] = *(const f16x8*)(XA + s * 32);

    __syncthreads();

    f16x8 bf[2][8];
#pragma unroll
    for (int tn = 0; tn < 2; ++tn)
#pragma unroll
        for (int s = 0; s < 8; ++s)
            bf[tn][s] = *(const f16x8*)(&bs[(tn * 16 + r16) * 272 + kseg * 8 + s * 32]);

    f32x4v acc[2];
    acc[0] = (f32x4v){0.f, 0.f, 0.f, 0.f};
    acc[1] = (f32x4v){0.f, 0.f, 0.f, 0.f};
#pragma unroll
    for (int s = 0; s < 8; ++s) {
        acc[0] = __builtin_amdgcn_mfma_f32_16x16x32_f16(af[s], bf[0][s], acc[0], 0, 0, 0);
        acc[1] = __builtin_amdgcn_mfma_f32_16x16x32_f16(af[s], bf[1][s], acc[1], 0, 0, 0);
    }

    float as0 = a_src[c0 + r16], as1 = a_src[c0 + 16 + r16];
    float ad0 = a_dst[c0 + r16], ad1 = a_dst[c0 + 16 + r16];
#pragma unroll
    for (int r = 0; r < 4; ++r) {
        float p = acc[0][r] * as0 + acc[1][r] * as1;
        float q = acc[0][r] * ad0 + acc[1][r] * ad1;
        p += __shfl_xor(p, 1); q += __shfl_xor(q, 1);
        p += __shfl_xor(p, 2); q += __shfl_xor(q, 2);
        p += __shfl_xor(p, 4); q += __shfl_xor(q, 4);
        p += __shfl_xor(p, 8); q += __shfl_xor(q, 8);
        int row = row0 + v * 16 + kseg * 4 + r;
        if (r16 == 0 && row < N_NODES) {
            ssrc[row * NH + wcol] = p;
            sdst[row * NH + wcol] = q;
        }
    }

#pragma unroll
    for (int tn = 0; tn < 2; ++tn)
#pragma unroll
        for (int r = 0; r < 4; ++r)
            hs[(v * 16 + kseg * 4 + r) * 40 + tn * 16 + r16] = (_Float16)acc[tn][r];
    __syncthreads();
    {
        int row = tid >> 2;
        int c8 = (tid & 3) * 8;
        if (row0 + row < N_NODES) {
            f16x8 xv = *(const f16x8*)&hs[row * 40 + c8];
            *(f16x8*)(Hh + (size_t)(row0 + row) * 256 + c0 + c8) = xv;
        }
    }
}

// ---------------- GEMM K=64(41 padded) via MFMA fp16, B-in-LDS, fused score dots ----------------
// same skeleton as gemm256h; 2 K-steps, 4 MFMAs/wave.

__global__ __launch_bounds__(256) void gemm41h(const _Float16* __restrict__ Xh,
                                               const _Float16* __restrict__ W1t,
                                               const float* __restrict__ a_src,
                                               const float* __restrict__ a_dst,
                                               _Float16* __restrict__ Hh,
                                               float* __restrict__ ssrc,
                                               float* __restrict__ sdst) {
    __shared__ _Float16 bs[32 * 72];    // B: 32 cols x 64 K, padded stride 72
    __shared__ _Float16 hs[64 * 40];
    int row0 = (blockIdx.x >> 3) * 64;
    int wcol = blockIdx.x & 7;
    int c0 = wcol * 32;
    int tid = threadIdx.x;
    int lane = tid & 63;
    int v = tid >> 6;
    int r16 = lane & 15;
    int kseg = lane >> 4;

    {   // stage B: 32 cols x 64 halfs = 256 chunks of 8
        int c = tid >> 3;
        int k = (tid & 7) * 8;
        f16x8 xv = *(const f16x8*)(W1t + (size_t)(c0 + c) * 64 + k);
        *(f16x8*)(&bs[c * 72 + k]) = xv;
    }

    int arow = row0 + v * 16 + r16;
    const _Float16* XA = Xh + (size_t)arow * 64 + kseg * 8;
    f16x8 af[2];
    af[0] = *(const f16x8*)(XA);
    af[1] = *(const f16x8*)(XA + 32);

    __syncthreads();

    f16x8 bf[2][2];
#pragma unroll
    for (int tn = 0; tn < 2; ++tn)
#pragma unroll
        for (int s = 0; s < 2; ++s)
            bf[tn][s] = *(const f16x8*)(&bs[(tn * 16 + r16) * 72 + kseg * 8 + s * 32]);

    f32x4v acc[2];
    acc[0] = (f32x4v){0.f, 0.f, 0.f, 0.f};
    acc[1] = (f32x4v){0.f, 0.f, 0.f, 0.f};
#pragma unroll
    for (int s = 0; s < 2; ++s) {
        acc[0] = __builtin_amdgcn_mfma_f32_16x16x32_f16(af[s], bf[0][s], acc[0], 0, 0, 0);
        acc[1] = __builtin_amdgcn_mfma_f32_16x16x32_f16(af[s], bf[1][s], acc[1], 0, 0, 0);
    }

    float as0 = a_src[c0 + r16], as1 = a_src[c0 + 16 + r16];
    float ad0 = a_dst[c0 + r16], ad1 = a_dst[c0 + 16 + r16];
#pragma unroll
    for (int r = 0; r < 4; ++r) {
        float p = acc[0][r] * as0 + acc[1][r] * as1;
        float q = acc[0][r] * ad0 + acc[1][r] * ad1;
        p += __shfl_xor(p, 1); q += __shfl_xor(q, 1);
        p += __shfl_xor(p, 2); q += __shfl_xor(q, 2);
        p += __shfl_xor(p, 4); q += __shfl_xor(q, 4);
        p += __shfl_xor(p, 8); q += __shfl_xor(q, 8);
        int row = row0 + v * 16 + kseg * 4 + r;
        if (r16 == 0 && row < N_NODES) {
            ssrc[row * NH + wcol] = p;
            sdst[row * NH + wcol] = q;
        }
    }

#pragma unroll
    for (int tn = 0; tn < 2; ++tn)
#pragma unroll
        for (int r = 0; r < 4; ++r)
            hs[(v * 16 + kseg * 4 + r) * 40 + tn * 16 + r16] = (_Float16)acc[tn][r];
    __syncthreads();
    {
        int row = tid >> 2;
        int c8 = (tid & 3) * 8;
        if (row0 + row < N_NODES) {
            f16x8 xv = *(const f16x8*)&hs[row * 40 + c8];
            *(f16x8*)(Hh + (size_t)(row0 + row) * 256 + c0 + c8) = xv;
        }
    }
}

// ---------------- fused GAT aggregation + bias + BN(eval) + ELU ----------------
// Single pass (softmax shift-invariance; scores O(1) -> exp safe in fp32).

__global__ __launch_bounds__(256) void gat_agg(const int* __restrict__ row_ptr,
                                               const int* __restrict__ colidx,
                                               const float* __restrict__ ssrc,
                                               const float* __restrict__ sdst,
                                               const _Float16* __restrict__ h,
                                               const float* __restrict__ bias,
                                               const float* __restrict__ gamma,
                                               const float* __restrict__ beta,
                                               _Float16* __restrict__ outh) {
    int wave = (blockIdx.x * blockDim.x + threadIdx.x) >> 6;
    int lane = threadIdx.x & 63;
    if (wave >= N_NODES) return;
    int n = wave;
    int beg = row_ptr[n], end = row_ptr[n + 1];
    int deg = end - beg;

    int hd = lane >> 3;
    float sd = sdst[n * NH + hd];
    int c = lane * 4;
    float acc0 = 0.f, acc1 = 0.f, acc2 = 0.f, acc3 = 0.f, denom = 0.f;

    int i = 0;
    for (; i + 8 <= deg; i += 8) {
        int sidx[8];
#pragma unroll
        for (int j = 0; j < 8; ++j) sidx[j] = colidx[beg + i + j];
        float wv[8];
#pragma unroll
        for (int j = 0; j < 8; ++j) {
            float v = ssrc[sidx[j] * NH + hd] + sd;
            v = (v >= 0.f) ? v : 0.2f * v;
            wv[j] = __expf(v);
        }
        f16x4 hv[8];
#pragma unroll
        for (int j = 0; j < 8; ++j) hv[j] = *reinterpret_cast<const f16x4*>(h + (size_t)sidx[j] * HC + c);
#pragma unroll
        for (int j = 0; j < 8; ++j) {
            denom += wv[j];
            acc0 += wv[j] * (float)hv[j][0];
            acc1 += wv[j] * (float)hv[j][1];
            acc2 += wv[j] * (float)hv[j][2];
            acc3 += wv[j] * (float)hv[j][3];
        }
    }
    for (; i < deg; ++i) {
        int s = colidx[beg + i];
        float v = ssrc[s * NH + hd] + sd;
        v = (v >= 0.f) ? v : 0.2f * v;
        float wgt = __expf(v);
        denom += wgt;
        const f16x4 hv = *reinterpret_cast<const f16x4*>(h + (size_t)s * HC + c);
        acc0 += wgt * (float)hv[0]; acc1 += wgt * (float)hv[1];
        acc2 += wgt * (float)hv[2]; acc3 += wgt * (float)hv[3];
    }
    float inv = 1.0f / denom;
    const float bninv = 0.99999500003749981f;  // 1/sqrt(1+1e-5)
    float vals[4] = {acc0, acc1, acc2, acc3};
    f16x4 o;
#pragma unroll
    for (int j = 0; j < 4; ++j) {
        float v = vals[j] * inv + bias[c + j];
        v = v * (gamma[c + j] * bninv) + beta[c + j];
        v = (v > 0.f) ? v : (__expf(v) - 1.0f);
        o[j] = (_Float16)v;
    }
    *(f16x4*)(outh + (size_t)n * HC + c) = o;
}

// ---------------- pooling ----------------

__global__ __launch_bounds__(256) void pool_partial(const _Float16* __restrict__ h,
                                                    const int* __restrict__ gstart,
                                                    const int* __restrict__ gend,
                                                    float* __restrict__ psum,
                                                    float* __restrict__ pmax) {
    int g = blockIdx.x >> 4;
    int c = blockIdx.x & (PCHUNK - 1);
    int t = threadIdx.x;
    int s = gstart[g], e = gend[g];
    int len = e - s;
    int n0 = s + (int)(((long long)len * c) / PCHUNK);
    int n1 = s + (int)(((long long)len * (c + 1)) / PCHUNK);
    float sum = 0.f, mx = -3.0e38f;
    for (int n = n0; n < n1; ++n) {
        float v = (float)h[(size_t)n * HC + t];
        sum += v;
        mx = fmaxf(mx, v);
    }
    psum[(size_t)(g * PCHUNK + c) * HC + t] = sum;
    pmax[(size_t)(g * PCHUNK + c) * HC + t] = mx;
}

// ---------------- MLP head (fused pool-finalize + 3 FC layers) ----------------

__global__ __launch_bounds__(256) void mlp(const float* __restrict__ psum,
                                           const float* __restrict__ pmax,
                                           const int* __restrict__ gstart,
                                           const int* __restrict__ gend,
                                           const float* __restrict__ gsz,
                                           const float* __restrict__ fc1wT, const float* __restrict__ fc1b,
                                           const float* __restrict__ gf1, const float* __restrict__ bf1,
                                           const float* __restrict__ fc2w, const float* __restrict__ fc2b,
                                           const float* __restrict__ gf2, const float* __restrict__ bf2,
                                           const float* __restrict__ fc3w, const float* __restrict__ fc3b,
                                           float* __restrict__ out) {
    __shared__ __align__(16) float pr[514];
    __shared__ float z1[64];
    __shared__ float zz2[8][32];
    __shared__ float z2[32];
    int g = blockIdx.x;
    int t = threadIdx.x;
    const float bninv = 0.99999500003749981f;

    {
        float s = 0.f, m = -3.0e38f;
#pragma unroll
        for (int c = 0; c < PCHUNK; ++c) {
            s += psum[(size_t)(g * PCHUNK + c) * HC + t];
            m = fmaxf(m, pmax[(size_t)(g * PCHUNK + c) * HC + t]);
        }
        float cnt = (float)(gend[g] - gstart[g]);
        pr[t] = s / fmaxf(cnt, 1.f);
        pr[256 + t] = m;
        if (t < 2) pr[512 + t] = gsz[g * 2 + t];
    }
    __syncthreads();

    {
        int wv = t >> 6, lane = t & 63;
        float4 pa = *reinterpret_cast<const float4*>(&pr[lane * 8]);
        float4 pb = *reinterpret_cast<const float4*>(&pr[lane * 8 + 4]);
#pragma unroll 4
        for (int i = 0; i < 16; ++i) {
            int u = wv * 16 + i;
            const float* wrow = fc1wT + u * 520;
            float4 wa = *reinterpret_cast<const float4*>(wrow + lane * 8);
            float4 wb = *reinterpret_cast<const float4*>(wrow + lane * 8 + 4);
            float a = pa.x * wa.x + pa.y * wa.y + pa.z * wa.z + pa.w * wa.w
                    + pb.x * wb.x + pb.y * wb.y + pb.z * wb.z + pb.w * wb.w;
            if (lane == 0) a += pr[512] * wrow[512] + pr[513] * wrow[513];
            a += __shfl_xor(a, 1); a += __shfl_xor(a, 2); a += __shfl_xor(a, 4);
            a += __shfl_xor(a, 8); a += __shfl_xor(a, 16); a += __shfl_xor(a, 32);
            if (lane == 0) {
                a += fc1b[u];
                a = a * (gf1[u] * bninv) + bf1[u];
                z1[u] = fmaxf(a, 0.f);
            }
        }
    }
    __syncthreads();

    {
        int u = t & 31, sp = t >> 5;
        float b = 0.f;
#pragma unroll
        for (int k = sp * 8; k < sp * 8 + 8; ++k) b += z1[k] * fc2w[k * 32 + u];
        zz2[sp][u] = b;
    }
    __syncthreads();
    if (t < 32) {
        float b = 0.f;
#pragma unroll
        for (int sp = 0; sp < 8; ++sp) b += zz2[sp][t];
        b += fc2b[t];
        b = b * (gf2[t] * bninv) + bf2[t];
        z2[t] = fmaxf(b, 0.f);
    }
    __syncthreads();

    if (t < 2) {
        float c = 0.f;
#pragma unroll
        for (int k = 0; k < 32; ++k) c += z2[k] * fc3w[k * 2 + t];
        out[g * 2 + t] = c + fc3b[t];
    }
}

// ---------------- launch ----------------

extern "C" void kernel_launch(void* const* d_in, const int* in_sizes, int n_in,
                              void* d_out, int out_size, void* d_ws, size_t ws_size,
                              hipStream_t stream) {
    const float* x    = (const float*)d_in[0];
    const int*   ei   = (const int*)d_in[1];
    const int*   batch= (const int*)d_in[2];
    const float* gsz  = (const float*)d_in[3];
    const float* W1   = (const float*)d_in[4];
    const float* as1  = (const float*)d_in[5];
    const float* ad1  = (const float*)d_in[6];
    const float* b1   = (const float*)d_in[7];
    const float* g1   = (const float*)d_in[8];
    const float* be1  = (const float*)d_in[9];
    const float* W2   = (const float*)d_in[10];
    const float* as2  = (const float*)d_in[11];
    const float* ad2  = (const float*)d_in[12];
    const float* b2   = (const float*)d_in[13];
    const float* g2   = (const float*)d_in[14];
    const float* be2  = (const float*)d_in[15];
    const float* fc1w = (const float*)d_in[16];
    const float* fc1b = (const float*)d_in[17];
    const float* gf1  = (const float*)d_in[18];
    const float* bf1  = (const float*)d_in[19];
    const float* fc2w = (const float*)d_in[20];
    const float* fc2b = (const float*)d_in[21];
    const float* gf2  = (const float*)d_in[22];
    const float* bf2  = (const float*)d_in[23];
    const float* fc3w = (const float*)d_in[24];
    const float* fc3b = (const float*)d_in[25];
    float* out = (float*)d_out;

    char* w = (char*)d_ws;
    _Float16* h_half   = (_Float16*)w; w += (size_t)N_NODES * HC * 2;   // 10.24 MB
    _Float16* act_half = (_Float16*)w; w += (size_t)N_NODES * HC * 2;   // 10.24 MB
    _Float16* act2_half= (_Float16*)w; w += (size_t)N_NODES * HC * 2;   // 10.24 MB
    _Float16* Wt       = (_Float16*)w; w += (size_t)HC * HC * 2;        // 128 KB
    _Float16* W1t      = (_Float16*)w; w += (size_t)HC * 64 * 2;        // 32 KB
    _Float16* xpad     = (_Float16*)w; w += (size_t)NPAD * 64 * 2;      // 2.56 MB
    float* fc1wT       = (float*)w;    w += (size_t)64 * 520 * 4;       // 133 KB
    float* ssrc        = (float*)w;    w += (size_t)N_NODES * NH * 4;
    float* sdst        = (float*)w;    w += (size_t)N_NODES * NH * 4;
    int* row_ptr  = (int*)w;   w += (size_t)(N_NODES + 1) * 4;
    int* cursor   = (int*)w;   w += (size_t)N_NODES * 4;
    // cnt, gstart, gend contiguous -> single memset
    int* cnt      = (int*)w;   w += (size_t)N_NODES * 4;
    int* gstart   = (int*)w;   w += 64 * 4;
    int* gend     = (int*)w;   w += 64 * 4;
    int* colidx   = (int*)w;   w += (size_t)(E_EDGES + N_NODES) * 4;
    int* partial  = (int*)w;   w += 64 * 4;

    // pool partials alias h_half (dead after gat_agg#2)
    float* psum = (float*)h_half;
    float* pmax = psum + (size_t)NG * PCHUNK * HC;

    hipMemsetAsync(cnt, 0, (size_t)(N_NODES + 128) * 4, stream);  // cnt + gstart + gend

    prep<<<914, 256, 0, stream>>>(W2, Wt, fc1w, fc1wT, batch, gstart, gend, W1, W1t, x, xpad);
    hist<<<1250, 256, 0, stream>>>(ei, cnt);
    scanA<<<40, 512, 0, stream>>>(cnt, partial);
    scanB<<<1, 64, 0, stream>>>(partial);
    scanC<<<40, 512, 0, stream>>>(cnt, partial, row_ptr, cursor, colidx);
    fill_csr<<<1250, 256, 0, stream>>>(ei, cursor, colidx);

    gemm41h<<<2504, 256, 0, stream>>>(xpad, W1t, as1, ad1, h_half, ssrc, sdst);
    gat_agg<<<5000, 256, 0, stream>>>(row_ptr, colidx, ssrc, sdst, h_half, b1, g1, be1, act_half);

    gemm256h<<<2504, 256, 0, stream>>>(act_half, Wt, as2, ad2, h_half, ssrc, sdst);
    gat_agg<<<5000, 256, 0, stream>>>(row_ptr, colidx, ssrc, sdst, h_half, b2, g2, be2, act2_half);

    pool_partial<<<NG * PCHUNK, 256, 0, stream>>>(act2_half, gstart, gend, psum, pmax);
    mlp<<<NG, 256, 0, stream>>>(psum, pmax, gstart, gend, gsz,
                                fc1wT, fc1b, gf1, bf1, fc2w, fc2b, gf2, bf2, fc3w, fc3b, out);
}